// Round 2
// 6096.156 us; speedup vs baseline: 1.4594x; 1.4594x over previous
//
#include <hip/hip_runtime.h>
#include <hip/hip_bf16.h>
#include <math.h>

#define BB 2
#define SS 2048
#define HH 4096
#define NH 32
#define NKV 8
#define HD 128
#define KVD (NKV*HD)    // 1024
#define WIN 512         // mask: j <= i && i-j <= 512
#define MROWS (BB*SS)   // 4096

#define DT_BF16 1
#define DT_F32  2

typedef __hip_bfloat16 bf16;
typedef __attribute__((ext_vector_type(8))) short short8;
typedef __attribute__((ext_vector_type(4))) float f32x4;

__device__ __forceinline__ float ldf(const bf16* p){ return __bfloat162float(*p); }
__device__ __forceinline__ float ldf(const float* p){ return *p; }
__device__ __forceinline__ void stf(bf16* p, float v){ *p = __float2bfloat16(v); }
__device__ __forceinline__ void stf(float* p, float v){ *p = v; }
__device__ __forceinline__ float b2f(unsigned short u){
  union { unsigned int i; float f; } x; x.i = ((unsigned int)u) << 16; return x.f;
}

// ---------- dtype detector (prior-session-proven) ----------
// fp32 buffers interpreted as uint16 halves: low halves carry random mantissa
// bits -> "exponent" field >=160 almost surely. Real bf16 weights never do.
__global__ void detect_kernel(const void* __restrict__ w, int* __restrict__ flag)
{
  __shared__ int big;
  if (threadIdx.x == 0) big = 0;
  __syncthreads();
  const unsigned short* u = (const unsigned short*)w;
  for (int i = threadIdx.x; i < 2048; i += 256) {
    int ex = (u[i] >> 7) & 0xFF;
    if (ex >= 160) big = 1;
  }
  __syncthreads();
  if (threadIdx.x == 0) *flag = big ? DT_F32 : DT_BF16;
}

// ------------- W [Kd,Nd] -> WT [Nd,Kd] bf16, dtype-gated -------------
template<typename TS>
__global__ __launch_bounds__(256)
void transpose_cvt(const int* __restrict__ flag, int mydt,
                   const TS* __restrict__ W, bf16* __restrict__ WT, int Kd, int Nd)
{
  if (*flag != mydt) return;
  __shared__ float tile[32][33];
  const int n0 = blockIdx.x*32, k0 = blockIdx.y*32;
  const int tx = threadIdx.x & 31, ty = threadIdx.x >> 5;   // ty 0..7
  #pragma unroll
  for (int j = 0; j < 4; j++)
    tile[ty + j*8][tx] = ldf(W + (size_t)(k0 + ty + j*8)*Nd + n0 + tx);
  __syncthreads();
  #pragma unroll
  for (int j = 0; j < 4; j++)
    WT[(size_t)(n0 + ty + j*8)*Kd + k0 + tx] = __float2bfloat16(tile[tx][ty + j*8]);
}

// ---------------- MFMA GEMM: C[M,N] = A[M,K] @ B^T ; dtype-gated ----------------
// A row-major [M,K] (bf16: global_load_lds direct; fp32: reg-stage + convert).
// B row-major bf16 [N,K] (pre-transposed weight), global_load_lds width 16.
// 128x128 tile, BK=32, 4 waves (2x2), 16x16x32 MFMA (m97 structure).
template<typename TA, typename TC>
__global__ __launch_bounds__(256)
void gemm_bt(const int* __restrict__ flag, int mydt,
             const TA* __restrict__ A, const bf16* __restrict__ Bm,
             TC* __restrict__ C, int M, int N, int K)
{
  if (*flag != mydt) return;
  __shared__ __align__(16) bf16 As[128*32];
  __shared__ __align__(16) bf16 Bs[128*32];
  const int tid  = threadIdx.x;
  const int w    = tid >> 6;
  const int lane = tid & 63;
  const int wr = w >> 1, wc = w & 1;
  const int tM = blockIdx.y*128, tN = blockIdx.x*128;
  const int srow = tid >> 2;          // 0..63
  const int scol = (tid & 3) * 8;     // 0,8,16,24
  const int fr = lane & 15;
  const int kq = (lane >> 4) * 8;

  f32x4 acc[4][4] = {};

  for (int k0 = 0; k0 < K; k0 += 32) {
    __syncthreads();
    #pragma unroll
    for (int q = 0; q < 2; q++) {
      const int row = q*64 + srow;
      const bf16* gb = Bm + (size_t)(tN + row)*K + k0 + scol;
      char* lb = (char*)Bs + q*4096 + w*1024;   // wave-uniform base; HW adds lane*16
      __builtin_amdgcn_global_load_lds((const __attribute__((address_space(1))) void*)gb,
                                       (__attribute__((address_space(3))) void*)lb, 16, 0, 0);
    }
    if constexpr (__is_same(TA, bf16)) {
      #pragma unroll
      for (int q = 0; q < 2; q++) {
        const int row = q*64 + srow;
        const bf16* ga = A + (size_t)(tM + row)*K + k0 + scol;
        char* la = (char*)As + q*4096 + w*1024;
        __builtin_amdgcn_global_load_lds((const __attribute__((address_space(1))) void*)ga,
                                         (__attribute__((address_space(3))) void*)la, 16, 0, 0);
      }
    } else {
      f32x4 va[2][2];
      #pragma unroll
      for (int q = 0; q < 2; q++) {
        const float* ga = (const float*)A + (size_t)(tM + q*64 + srow)*K + k0 + scol;
        va[q][0] = *(const f32x4*)ga;
        va[q][1] = *(const f32x4*)(ga + 4);
      }
      #pragma unroll
      for (int q = 0; q < 2; q++) {
        union { short8 s; bf16 h[8]; } u;
        #pragma unroll
        for (int j = 0; j < 4; j++) {
          u.h[j]     = __float2bfloat16(va[q][0][j]);
          u.h[j + 4] = __float2bfloat16(va[q][1][j]);
        }
        *(short8*)((char*)As + q*4096 + tid*16) = u.s;
      }
    }
    __syncthreads();

    short8 af[4], bfr[4];
    #pragma unroll
    for (int m = 0; m < 4; m++) af[m]  = *(const short8*)&As[(wr*64 + m*16 + fr)*32 + kq];
    #pragma unroll
    for (int n = 0; n < 4; n++) bfr[n] = *(const short8*)&Bs[(wc*64 + n*16 + fr)*32 + kq];
    #pragma unroll
    for (int m = 0; m < 4; m++)
      #pragma unroll
      for (int n = 0; n < 4; n++)
        acc[m][n] = __builtin_amdgcn_mfma_f32_16x16x32_bf16(af[m], bfr[n], acc[m][n], 0, 0, 0);
  }

  // C/D layout (m89/m91-verified): col = lane&15, row = (lane>>4)*4 + reg
  const int fq = lane >> 4;
  #pragma unroll
  for (int m = 0; m < 4; m++)
    #pragma unroll
    for (int n = 0; n < 4; n++)
      #pragma unroll
      for (int r = 0; r < 4; r++)
        stf(C + (size_t)(tM + wr*64 + m*16 + fq*4 + r)*N + (tN + wc*64 + n*16 + fr),
            acc[m][n][r]);
}

// ---------------- RoPE (in place, bf16 [MROWS, nh*HD]) ----------------
__global__ void rope_kernel(bf16* __restrict__ X, int nh)
{
  int idx = blockIdx.x*blockDim.x + threadIdx.x;
  int total = MROWS * nh * 64;
  if (idx >= total) return;
  int f   = idx & 63;
  int h   = (idx >> 6) % nh;
  int row = (idx >> 6) / nh;
  int s   = row & (SS - 1);
  float ang = (float)s * powf(10000.0f, -(float)f * (1.0f/64.0f));
  float cv = cosf(ang), sv = sinf(ang);
  size_t base = (size_t)row*nh*HD + (size_t)h*HD;
  float x1 = ldf(X + base + f), x2 = ldf(X + base + 64 + f);
  stf(X + base + f,      x1*cv - x2*sv);
  stf(X + base + 64 + f, x2*cv + x1*sv);
}

// ---------------- Attention: one block per (b, h, i); 256 threads ----------------
__global__ __launch_bounds__(256)
void attn_kernel(const bf16* __restrict__ Q, const bf16* __restrict__ K,
                 const bf16* __restrict__ V, bf16* __restrict__ Aout)
{
  const int i = blockIdx.x;
  const int h = blockIdx.y;
  const int b = blockIdx.z;
  const int kh = h >> 2;            // GQA: 4 q-heads per kv head
  const int t = threadIdx.x;        // 0..255

  __shared__ __align__(16) float qs[HD];
  __shared__ float sc[WIN + 1];
  __shared__ float red[256];
  __shared__ float redA[256];
  __shared__ float redB[256];

  const int jlo = (i > WIN) ? (i - WIN) : 0;
  const int nj  = i - jlo + 1;

  if (t < HD) qs[t] = ldf(Q + (size_t)(b*SS + i)*HH + (size_t)h*HD + t);
  __syncthreads();

  const float scale = 0.08838834764831845f;   // 1/sqrt(128)

  float lmax = -1e30f;
  for (int jj = t; jj < nj; jj += 256) {
    const short8* kr = (const short8*)(K + (size_t)(b*SS + jlo + jj)*KVD + (size_t)kh*HD);
    float dot = 0.f;
    #pragma unroll
    for (int u = 0; u < 16; u++) {
      short8 kv = kr[u];
      const f32x4 q0 = *(const f32x4*)&qs[u*8];
      const f32x4 q1 = *(const f32x4*)&qs[u*8 + 4];
      dot = fmaf(q0[0], b2f((unsigned short)kv[0]), dot);
      dot = fmaf(q0[1], b2f((unsigned short)kv[1]), dot);
      dot = fmaf(q0[2], b2f((unsigned short)kv[2]), dot);
      dot = fmaf(q0[3], b2f((unsigned short)kv[3]), dot);
      dot = fmaf(q1[0], b2f((unsigned short)kv[4]), dot);
      dot = fmaf(q1[1], b2f((unsigned short)kv[5]), dot);
      dot = fmaf(q1[2], b2f((unsigned short)kv[6]), dot);
      dot = fmaf(q1[3], b2f((unsigned short)kv[7]), dot);
    }
    dot *= scale;
    sc[jj] = dot;
    lmax = fmaxf(lmax, dot);
  }
  red[t] = lmax; __syncthreads();
  #pragma unroll
  for (int off = 128; off > 0; off >>= 1) {
    if (t < off) red[t] = fmaxf(red[t], red[t + off]);
    __syncthreads();
  }
  const float m = red[0];
  __syncthreads();

  float lsum = 0.f;
  for (int jj = t; jj < nj; jj += 256) {
    float e = __expf(sc[jj] - m);
    sc[jj] = e;
    lsum += e;
  }
  red[t] = lsum; __syncthreads();
  #pragma unroll
  for (int off = 128; off > 0; off >>= 1) {
    if (t < off) red[t] += red[t + off];
    __syncthreads();
  }
  const float linv = 1.0f / red[0];
  __syncthreads();

  // PV: 4 j-chunks x 64 lanes x 2 dims -> dependent-chain length ~nj/4
  const int c  = t >> 6;
  const int d2 = (t & 63) * 2;
  float a0 = 0.f, a1 = 0.f;
  for (int jj = c; jj < nj; jj += 4) {
    const unsigned int u = *(const unsigned int*)(V + (size_t)(b*SS + jlo + jj)*KVD
                                                    + (size_t)kh*HD + d2);
    const float p = sc[jj];
    a0 = fmaf(p, b2f((unsigned short)(u & 0xFFFFu)), a0);
    a1 = fmaf(p, b2f((unsigned short)(u >> 16)), a1);
  }
  redA[t] = a0; redB[t] = a1; __syncthreads();
  if (t < 64) {
    float o0 = (redA[t] + redA[t+64] + redA[t+128] + redA[t+192]) * linv;
    float o1 = (redB[t] + redB[t+64] + redB[t+128] + redB[t+192]) * linv;
    bf16* op = Aout + (size_t)(b*SS + i)*HH + (size_t)h*HD + d2;
    stf(op, o0); stf(op + 1, o1);
  }
}

extern "C" void kernel_launch(void* const* d_in, const int* in_sizes, int n_in,
                              void* d_out, int out_size, void* d_ws, size_t ws_size,
                              hipStream_t stream)
{
  // Workspace: prior-proven 80 MB + 256 B footprint.
  // flag @ 0 | Q @ 256 (32MB) | K (8MB) | V (8MB) | S (32MB).
  // S time-shares: WTq -> WTk -> WTv -> attention output A.
  // WTo reuses the Q region (Q dead after attn).
  char* ws = (char*)d_ws;
  const size_t MB = (size_t)1 << 20;
  int*  flag = (int*)ws;
  bf16* Q  = (bf16*)(ws + 256);
  bf16* K  = (bf16*)(ws + 256 + 32*MB);
  bf16* V  = (bf16*)(ws + 256 + 40*MB);
  bf16* S  = (bf16*)(ws + 256 + 48*MB);
  bf16* WTo = Q;

  detect_kernel<<<1, 256, 0, stream>>>(d_in[1], flag);

  auto tr = [&](const void* W, int Kd, int Nd, bf16* dst){
    dim3 g(Nd/32, Kd/32);
    transpose_cvt<bf16 ><<<g,256,0,stream>>>(flag, DT_BF16, (const bf16 *)W, dst, Kd, Nd);
    transpose_cvt<float><<<g,256,0,stream>>>(flag, DT_F32 , (const float*)W, dst, Kd, Nd);
  };

  // ---- projections: Q/K/V (bf16 out in both modes) ----
  tr(d_in[1], HH, HH, S);
  gemm_bt<bf16 ,bf16><<<dim3(HH/128,  MROWS/128),256,0,stream>>>(flag, DT_BF16, (const bf16 *)d_in[0], S, Q, MROWS, HH, HH);
  gemm_bt<float,bf16><<<dim3(HH/128,  MROWS/128),256,0,stream>>>(flag, DT_F32 , (const float*)d_in[0], S, Q, MROWS, HH, HH);

  tr(d_in[2], HH, KVD, S);
  gemm_bt<bf16 ,bf16><<<dim3(KVD/128, MROWS/128),256,0,stream>>>(flag, DT_BF16, (const bf16 *)d_in[0], S, K, MROWS, KVD, HH);
  gemm_bt<float,bf16><<<dim3(KVD/128, MROWS/128),256,0,stream>>>(flag, DT_F32 , (const float*)d_in[0], S, K, MROWS, KVD, HH);

  tr(d_in[3], HH, KVD, S);
  gemm_bt<bf16 ,bf16><<<dim3(KVD/128, MROWS/128),256,0,stream>>>(flag, DT_BF16, (const bf16 *)d_in[0], S, V, MROWS, KVD, HH);
  gemm_bt<float,bf16><<<dim3(KVD/128, MROWS/128),256,0,stream>>>(flag, DT_F32 , (const float*)d_in[0], S, V, MROWS, KVD, HH);

  // ---- dtype-independent middle ----
  rope_kernel<<<(MROWS*NH *64 + 255)/256, 256, 0, stream>>>(Q, NH);
  rope_kernel<<<(MROWS*NKV*64 + 255)/256, 256, 0, stream>>>(K, NKV);
  attn_kernel<<<dim3(SS, NH, BB), 256, 0, stream>>>(Q, K, V, S);   // A -> S

  // ---- output projection (dtype of output follows input dtype) ----
  tr(d_in[4], HH, HH, WTo);
  gemm_bt<bf16,bf16 ><<<dim3(HH/128, MROWS/128),256,0,stream>>>(flag, DT_BF16, S, WTo, (bf16 *)d_out, MROWS, HH, HH);
  gemm_bt<bf16,float><<<dim3(HH/128, MROWS/128),256,0,stream>>>(flag, DT_F32 , S, WTo, (float*)d_out, MROWS, HH, HH);
}

// Round 3
// 1086.941 us; speedup vs baseline: 8.1850x; 5.6085x over previous
//
#include <hip/hip_runtime.h>
#include <hip/hip_bf16.h>
#include <math.h>

#define BB 2
#define SS 2048
#define HH 4096
#define NH 32
#define NKV 8
#define HD 128
#define KVD (NKV*HD)    // 1024
#define WIN 512         // mask: j <= i && i-j <= 512
#define MROWS (BB*SS)   // 4096

#define DT_BF16 1
#define DT_F32  2

typedef __hip_bfloat16 bf16;
typedef __attribute__((ext_vector_type(8))) short short8;
typedef __attribute__((ext_vector_type(4))) float f32x4;

__device__ __forceinline__ float ldf(const bf16* p){ return __bfloat162float(*p); }
__device__ __forceinline__ float ldf(const float* p){ return *p; }
__device__ __forceinline__ void stf(bf16* p, float v){ *p = __float2bfloat16(v); }
__device__ __forceinline__ void stf(float* p, float v){ *p = v; }

// ---------- dtype detector (prior-session-proven) ----------
__global__ void detect_kernel(const void* __restrict__ w, int* __restrict__ flag)
{
  __shared__ int big;
  if (threadIdx.x == 0) big = 0;
  __syncthreads();
  const unsigned short* u = (const unsigned short*)w;
  for (int i = threadIdx.x; i < 2048; i += 256) {
    int ex = (u[i] >> 7) & 0xFF;
    if (ex >= 160) big = 1;
  }
  __syncthreads();
  if (threadIdx.x == 0) *flag = big ? DT_F32 : DT_BF16;
}

// ------------- W [Kd,Nd] -> WT [Nd,Kd] bf16, dtype-gated -------------
template<typename TS>
__global__ __launch_bounds__(256)
void transpose_cvt(const int* __restrict__ flag, int mydt,
                   const TS* __restrict__ W, bf16* __restrict__ WT, int Kd, int Nd)
{
  if (*flag != mydt) return;
  __shared__ float tile[32][33];
  const int n0 = blockIdx.x*32, k0 = blockIdx.y*32;
  const int tx = threadIdx.x & 31, ty = threadIdx.x >> 5;   // ty 0..7
  #pragma unroll
  for (int j = 0; j < 4; j++)
    tile[ty + j*8][tx] = ldf(W + (size_t)(k0 + ty + j*8)*Nd + n0 + tx);
  __syncthreads();
  #pragma unroll
  for (int j = 0; j < 4; j++)
    WT[(size_t)(n0 + ty + j*8)*Kd + k0 + tx] = __float2bfloat16(tile[tx][ty + j*8]);
}

// ---------------- MFMA GEMM: C[M,N] = A[M,K] @ B^T ; dtype-gated ----------------
// VTRANS=1: C is written transposed into VT[b][kh][d][s] (bf16), for the V proj.
template<typename TA, typename TC, int VTRANS>
__global__ __launch_bounds__(256)
void gemm_bt(const int* __restrict__ flag, int mydt,
             const TA* __restrict__ A, const bf16* __restrict__ Bm,
             TC* __restrict__ C, int M, int N, int K)
{
  if (*flag != mydt) return;
  __shared__ __align__(16) bf16 As[128*32];
  __shared__ __align__(16) bf16 Bs[128*32];
  const int tid  = threadIdx.x;
  const int w    = tid >> 6;
  const int lane = tid & 63;
  const int wr = w >> 1, wc = w & 1;
  const int tM = blockIdx.y*128, tN = blockIdx.x*128;
  const int srow = tid >> 2;          // 0..63
  const int scol = (tid & 3) * 8;     // 0,8,16,24
  const int fr = lane & 15;
  const int kq = (lane >> 4) * 8;

  f32x4 acc[4][4] = {};

  for (int k0 = 0; k0 < K; k0 += 32) {
    __syncthreads();
    #pragma unroll
    for (int q = 0; q < 2; q++) {
      const int row = q*64 + srow;
      const bf16* gb = Bm + (size_t)(tN + row)*K + k0 + scol;
      char* lb = (char*)Bs + q*4096 + w*1024;   // wave-uniform base; HW adds lane*16
      __builtin_amdgcn_global_load_lds((const __attribute__((address_space(1))) void*)gb,
                                       (__attribute__((address_space(3))) void*)lb, 16, 0, 0);
    }
    if constexpr (__is_same(TA, bf16)) {
      #pragma unroll
      for (int q = 0; q < 2; q++) {
        const int row = q*64 + srow;
        const bf16* ga = A + (size_t)(tM + row)*K + k0 + scol;
        char* la = (char*)As + q*4096 + w*1024;
        __builtin_amdgcn_global_load_lds((const __attribute__((address_space(1))) void*)ga,
                                         (__attribute__((address_space(3))) void*)la, 16, 0, 0);
      }
    } else {
      f32x4 va[2][2];
      #pragma unroll
      for (int q = 0; q < 2; q++) {
        const float* ga = (const float*)A + (size_t)(tM + q*64 + srow)*K + k0 + scol;
        va[q][0] = *(const f32x4*)ga;
        va[q][1] = *(const f32x4*)(ga + 4);
      }
      #pragma unroll
      for (int q = 0; q < 2; q++) {
        union { short8 s; bf16 h[8]; } u;
        #pragma unroll
        for (int j = 0; j < 4; j++) {
          u.h[j]     = __float2bfloat16(va[q][0][j]);
          u.h[j + 4] = __float2bfloat16(va[q][1][j]);
        }
        *(short8*)((char*)As + q*4096 + tid*16) = u.s;
      }
    }
    __syncthreads();

    short8 af[4], bfr[4];
    #pragma unroll
    for (int m = 0; m < 4; m++) af[m]  = *(const short8*)&As[(wr*64 + m*16 + fr)*32 + kq];
    #pragma unroll
    for (int n = 0; n < 4; n++) bfr[n] = *(const short8*)&Bs[(wc*64 + n*16 + fr)*32 + kq];
    #pragma unroll
    for (int m = 0; m < 4; m++)
      #pragma unroll
      for (int n = 0; n < 4; n++)
        acc[m][n] = __builtin_amdgcn_mfma_f32_16x16x32_bf16(af[m], bfr[n], acc[m][n], 0, 0, 0);
  }

  // C/D layout: col = lane&15, row = (lane>>4)*4 + reg
  const int fq = lane >> 4;
  #pragma unroll
  for (int m = 0; m < 4; m++)
    #pragma unroll
    for (int n = 0; n < 4; n++)
      #pragma unroll
      for (int r = 0; r < 4; r++) {
        const int gm = tM + wr*64 + m*16 + fq*4 + r;
        const int gn = tN + wc*64 + n*16 + fr;
        if constexpr (VTRANS) {
          // VT[b][kh][d][s]: b=gm>>11, s=gm&2047, kh=gn>>7, d=gn&127
          size_t idx = ((size_t)((gm >> 11)*NKV + (gn >> 7)))*((size_t)HD*SS)
                     + (size_t)(gn & 127)*SS + (gm & 2047);
          stf((bf16*)C + idx, acc[m][n][r]);
        } else {
          stf(C + (size_t)gm*N + gn, acc[m][n][r]);
        }
      }
}

// ---------------- RoPE (in place, bf16 [MROWS, nh*HD]) ----------------
__global__ void rope_kernel(bf16* __restrict__ X, int nh)
{
  int idx = blockIdx.x*blockDim.x + threadIdx.x;
  int total = MROWS * nh * 64;
  if (idx >= total) return;
  int f   = idx & 63;
  int h   = (idx >> 6) % nh;
  int row = (idx >> 6) / nh;
  int s   = row & (SS - 1);
  float ang = (float)s * powf(10000.0f, -(float)f * (1.0f/64.0f));
  float cv = cosf(ang), sv = sinf(ang);
  size_t base = (size_t)row*nh*HD + (size_t)h*HD;
  float x1 = ldf(X + base + f), x2 = ldf(X + base + 64 + f);
  stf(X + base + f,      x1*cv - x2*sv);
  stf(X + base + 64 + f, x2*cv + x1*sv);
}

// ---------------- Flash-tile MFMA attention ----------------
// Block = (b, h, 64-row q-tile); 4 waves x 16 q-rows; KV tiles of 64.
// Q,K staged [64][128] swizzled (byte ^= (row&7)<<4, m214 recipe); V^T staged
// [128][64] swizzled from the pre-transposed VT buffer; P via per-wave
// swizzled 2KB LDS round-trip to reach A-operand layout.
__global__ __launch_bounds__(256, 2)
void attn_mfma(const bf16* __restrict__ Q, const bf16* __restrict__ K,
               const bf16* __restrict__ VT, bf16* __restrict__ Aout)
{
  const int i0 = blockIdx.x * 64;
  const int h  = blockIdx.y;
  const int b  = blockIdx.z;
  const int kh = h >> 2;
  const int tid = threadIdx.x;
  const int w = tid >> 6, lane = tid & 63;
  const int fr = lane & 15, fq = lane >> 4;

  __shared__ __align__(16) bf16 Qs[64*128];
  __shared__ __align__(16) bf16 Ks[64*128];
  __shared__ __align__(16) bf16 Vs[128*64];
  __shared__ __align__(16) bf16 Ps[4][16*64];

  // ---- stage Q tile (once), swizzled ----
  {
    const bf16* gq = Q + (size_t)(b*SS + i0)*HH + h*HD;
    #pragma unroll
    for (int it = 0; it < 4; it++) {
      int slot = tid + it*256;
      int r = slot >> 4, cg = slot & 15;
      short8 v = *(const short8*)(gq + (size_t)r*HH + cg*8);
      *(short8*)((char*)Qs + r*256 + ((cg*16) ^ ((r & 7) << 4))) = v;
    }
  }
  __syncthreads();

  // Q A-fragments (registers, reused across all KV tiles)
  short8 qf[4];
  {
    const int qrow = w*16 + fr;
    #pragma unroll
    for (int kk = 0; kk < 4; kk++)
      qf[kk] = *(const short8*)((char*)Qs + qrow*256 + ((kk*64 + fq*16) ^ ((qrow & 7) << 4)));
  }

  const float scale = 0.08838834764831845f;   // 1/sqrt(128)
  f32x4 o[8];
  #pragma unroll
  for (int nn = 0; nn < 8; nn++) o[nn] = (f32x4){0.f, 0.f, 0.f, 0.f};
  float m_run[4] = {-1e30f, -1e30f, -1e30f, -1e30f};
  float l_run[4] = {0.f, 0.f, 0.f, 0.f};

  const int j0_lo = (i0 >= WIN) ? (i0 - WIN) : 0;

  for (int j0 = j0_lo; j0 <= i0; j0 += 64) {
    __syncthreads();
    // ---- stage K tile [64][128] swizzled ----
    {
      const bf16* gk = K + (size_t)(b*SS + j0)*KVD + kh*HD;
      #pragma unroll
      for (int it = 0; it < 4; it++) {
        int slot = tid + it*256;
        int r = slot >> 4, cg = slot & 15;
        short8 v = *(const short8*)(gk + (size_t)r*KVD + cg*8);
        *(short8*)((char*)Ks + r*256 + ((cg*16) ^ ((r & 7) << 4))) = v;
      }
    }
    // ---- stage V^T tile [128][64] swizzled ----
    {
      const bf16* gv = VT + ((size_t)(b*NKV + kh)*HD)*SS + j0;
      #pragma unroll
      for (int it = 0; it < 4; it++) {
        int slot = tid + it*256;
        int d = slot >> 3, jg = slot & 7;
        short8 v = *(const short8*)(gv + (size_t)d*SS + jg*8);
        *(short8*)((char*)Vs + d*128 + ((jg*16) ^ ((d & 7) << 4))) = v;
      }
    }
    __syncthreads();

    // ---- QK^T: S[q=fq*4+r][j=jf*16+fr] ----
    f32x4 sv[4];
    #pragma unroll
    for (int jf = 0; jf < 4; jf++) sv[jf] = (f32x4){0.f, 0.f, 0.f, 0.f};
    #pragma unroll
    for (int kk = 0; kk < 4; kk++) {
      #pragma unroll
      for (int jf = 0; jf < 4; jf++) {
        const int krow = jf*16 + fr;
        short8 kf = *(const short8*)((char*)Ks + krow*256 + ((kk*64 + fq*16) ^ ((krow & 7) << 4)));
        sv[jf] = __builtin_amdgcn_mfma_f32_16x16x32_bf16(qf[kk], kf, sv[jf], 0, 0, 0);
      }
    }

    // ---- scale + mask ----
    const bool needmask = !((j0 >= i0 - 448) && (j0 <= i0 - 64));
    #pragma unroll
    for (int jf = 0; jf < 4; jf++)
      #pragma unroll
      for (int r = 0; r < 4; r++) {
        float x = sv[jf][r] * scale;
        if (needmask) {
          int iq = i0 + w*16 + fq*4 + r;
          int jv = j0 + jf*16 + fr;
          if (jv > iq || iq - jv > WIN) x = -1e30f;
        }
        sv[jf][r] = x;
      }

    // ---- online softmax (rows q = fq*4+r; reduce over jf in-reg + 16-lane xor) ----
    float fac[4];
    #pragma unroll
    for (int r = 0; r < 4; r++) {
      float t = fmaxf(fmaxf(sv[0][r], sv[1][r]), fmaxf(sv[2][r], sv[3][r]));
      t = fmaxf(t, __shfl_xor(t, 1));
      t = fmaxf(t, __shfl_xor(t, 2));
      t = fmaxf(t, __shfl_xor(t, 4));
      t = fmaxf(t, __shfl_xor(t, 8));
      float mn = fmaxf(m_run[r], t);
      fac[r] = __expf(m_run[r] - mn);
      m_run[r] = mn;
    }
    #pragma unroll
    for (int r = 0; r < 4; r++) {
      float sum = 0.f;
      #pragma unroll
      for (int jf = 0; jf < 4; jf++) {
        float p = __expf(sv[jf][r] - m_run[r]);
        sv[jf][r] = p;
        sum += p;
      }
      sum += __shfl_xor(sum, 1);
      sum += __shfl_xor(sum, 2);
      sum += __shfl_xor(sum, 4);
      sum += __shfl_xor(sum, 8);
      l_run[r] = l_run[r]*fac[r] + sum;
    }

    // ---- P -> per-wave LDS (swizzled), reach A-operand layout ----
    char* pbase = (char*)(&Ps[w][0]);
    #pragma unroll
    for (int jf = 0; jf < 4; jf++)
      #pragma unroll
      for (int r = 0; r < 4; r++) {
        int q = fq*4 + r, j = jf*16 + fr;
        *(bf16*)(pbase + q*128 + ((j*2) ^ ((q & 7) << 4))) = __float2bfloat16(sv[jf][r]);
      }

    // ---- rescale O, then PV ----
    #pragma unroll
    for (int nn = 0; nn < 8; nn++)
      #pragma unroll
      for (int r = 0; r < 4; r++) o[nn][r] *= fac[r];

    #pragma unroll
    for (int kt = 0; kt < 2; kt++) {
      short8 ap = *(const short8*)(pbase + fr*128 + ((kt*64 + fq*16) ^ ((fr & 7) << 4)));
      #pragma unroll
      for (int nn = 0; nn < 8; nn++) {
        const int d = nn*16 + fr;
        short8 vf = *(const short8*)((char*)Vs + d*128 + ((kt*64 + fq*16) ^ ((d & 7) << 4)));
        o[nn] = __builtin_amdgcn_mfma_f32_16x16x32_bf16(ap, vf, o[nn], 0, 0, 0);
      }
    }
  }

  // ---- epilogue: O / l ----
  float inv[4];
  #pragma unroll
  for (int r = 0; r < 4; r++) inv[r] = 1.0f / l_run[r];
  bf16* ao = Aout + (size_t)(b*SS + i0 + w*16)*HH + h*HD;
  #pragma unroll
  for (int nn = 0; nn < 8; nn++)
    #pragma unroll
    for (int r = 0; r < 4; r++)
      stf(ao + (size_t)(fq*4 + r)*HH + nn*16 + fr, o[nn][r] * inv[r]);
}

extern "C" void kernel_launch(void* const* d_in, const int* in_sizes, int n_in,
                              void* d_out, int out_size, void* d_ws, size_t ws_size,
                              hipStream_t stream)
{
  // Workspace (80 MB + 256 B, prior-proven footprint):
  // flag @0 | Q @256 (32MB) | K (8MB) | VT (8MB) | S (32MB).
  // S time-shares: WTq -> WTk -> WTv -> attention output A. WTo reuses Q region.
  char* ws = (char*)d_ws;
  const size_t MB = (size_t)1 << 20;
  int*  flag = (int*)ws;
  bf16* Q  = (bf16*)(ws + 256);
  bf16* K  = (bf16*)(ws + 256 + 32*MB);
  bf16* VT = (bf16*)(ws + 256 + 40*MB);
  bf16* S  = (bf16*)(ws + 256 + 48*MB);
  bf16* WTo = Q;

  detect_kernel<<<1, 256, 0, stream>>>(d_in[1], flag);

  auto tr = [&](const void* W, int Kd, int Nd, bf16* dst){
    dim3 g(Nd/32, Kd/32);
    transpose_cvt<bf16 ><<<g,256,0,stream>>>(flag, DT_BF16, (const bf16 *)W, dst, Kd, Nd);
    transpose_cvt<float><<<g,256,0,stream>>>(flag, DT_F32 , (const float*)W, dst, Kd, Nd);
  };

  // ---- projections ----
  tr(d_in[1], HH, HH, S);
  gemm_bt<bf16 ,bf16,0><<<dim3(HH/128,  MROWS/128),256,0,stream>>>(flag, DT_BF16, (const bf16 *)d_in[0], S, Q, MROWS, HH, HH);
  gemm_bt<float,bf16,0><<<dim3(HH/128,  MROWS/128),256,0,stream>>>(flag, DT_F32 , (const float*)d_in[0], S, Q, MROWS, HH, HH);

  tr(d_in[2], HH, KVD, S);
  gemm_bt<bf16 ,bf16,0><<<dim3(KVD/128, MROWS/128),256,0,stream>>>(flag, DT_BF16, (const bf16 *)d_in[0], S, K, MROWS, KVD, HH);
  gemm_bt<float,bf16,0><<<dim3(KVD/128, MROWS/128),256,0,stream>>>(flag, DT_F32 , (const float*)d_in[0], S, K, MROWS, KVD, HH);

  // V projection writes V^T directly (VT[b][kh][d][s])
  tr(d_in[3], HH, KVD, S);
  gemm_bt<bf16 ,bf16,1><<<dim3(KVD/128, MROWS/128),256,0,stream>>>(flag, DT_BF16, (const bf16 *)d_in[0], S, VT, MROWS, KVD, HH);
  gemm_bt<float,bf16,1><<<dim3(KVD/128, MROWS/128),256,0,stream>>>(flag, DT_F32 , (const float*)d_in[0], S, VT, MROWS, KVD, HH);

  // ---- dtype-independent middle ----
  rope_kernel<<<(MROWS*NH *64 + 255)/256, 256, 0, stream>>>(Q, NH);
  rope_kernel<<<(MROWS*NKV*64 + 255)/256, 256, 0, stream>>>(K, NKV);
  attn_mfma<<<dim3(SS/64, NH, BB), 256, 0, stream>>>(Q, K, VT, S);   // A -> S

  // ---- output projection (output dtype follows input dtype) ----
  tr(d_in[4], HH, HH, WTo);
  gemm_bt<bf16,bf16 ,0><<<dim3(HH/128, MROWS/128),256,0,stream>>>(flag, DT_BF16, S, WTo, (bf16 *)d_out, MROWS, HH, HH);
  gemm_bt<bf16,float,0><<<dim3(HH/128, MROWS/128),256,0,stream>>>(flag, DT_F32 , S, WTo, (float*)d_out, MROWS, HH, HH);
}

// Round 4
// 947.853 us; speedup vs baseline: 9.3861x; 1.1467x over previous
//
#include <hip/hip_runtime.h>
#include <hip/hip_bf16.h>
#include <math.h>

#define BB 2
#define SS 2048
#define HH 4096
#define NH 32
#define NKV 8
#define HD 128
#define KVD (NKV*HD)    // 1024
#define WIN 512         // mask: j <= i && i-j <= 512
#define MROWS (BB*SS)   // 4096

#define DT_BF16 1
#define DT_F32  2

typedef __hip_bfloat16 bf16;
typedef __attribute__((ext_vector_type(8))) short short8;
typedef __attribute__((ext_vector_type(4))) float f32x4;

__device__ __forceinline__ float ldf(const bf16* p){ return __bfloat162float(*p); }
__device__ __forceinline__ float ldf(const float* p){ return *p; }
__device__ __forceinline__ void stf(bf16* p, float v){ *p = __float2bfloat16(v); }
__device__ __forceinline__ void stf(float* p, float v){ *p = v; }

// ---------- dtype detector (prior-session-proven) ----------
__global__ void detect_kernel(const void* __restrict__ w, int* __restrict__ flag)
{
  __shared__ int big;
  if (threadIdx.x == 0) big = 0;
  __syncthreads();
  const unsigned short* u = (const unsigned short*)w;
  for (int i = threadIdx.x; i < 2048; i += 256) {
    int ex = (u[i] >> 7) & 0xFF;
    if (ex >= 160) big = 1;
  }
  __syncthreads();
  if (threadIdx.x == 0) *flag = big ? DT_F32 : DT_BF16;
}

// ---------- X fp32 -> bf16 (gated: fp32 mode only; Y = d_out scratch) ----------
__global__ __launch_bounds__(256)
void cvt_x(const int* __restrict__ flag, const float* __restrict__ X,
           bf16* __restrict__ Y)
{
  if (*flag != DT_F32) return;
  const size_t idx = (size_t)blockIdx.x*256 + threadIdx.x;   // 8 floats/thread
  const f32x4 a = *(const f32x4*)(X + idx*8);
  const f32x4 b = *(const f32x4*)(X + idx*8 + 4);
  union { short8 s; bf16 h[8]; } u;
  #pragma unroll
  for (int j = 0; j < 4; j++) {
    u.h[j]     = __float2bfloat16(a[j]);
    u.h[j + 4] = __float2bfloat16(b[j]);
  }
  *(short8*)(Y + idx*8) = u.s;
}

// ------------- W [Kd,Nd] -> WT [Nd,Kd] bf16, dtype-gated -------------
template<typename TS>
__global__ __launch_bounds__(256)
void transpose_cvt(const int* __restrict__ flag, int mydt,
                   const TS* __restrict__ W, bf16* __restrict__ WT, int Kd, int Nd)
{
  if (*flag != mydt) return;
  __shared__ float tile[32][33];
  const int n0 = blockIdx.x*32, k0 = blockIdx.y*32;
  const int tx = threadIdx.x & 31, ty = threadIdx.x >> 5;   // ty 0..7
  #pragma unroll
  for (int j = 0; j < 4; j++)
    tile[ty + j*8][tx] = ldf(W + (size_t)(k0 + ty + j*8)*Nd + n0 + tx);
  __syncthreads();
  #pragma unroll
  for (int j = 0; j < 4; j++)
    WT[(size_t)(n0 + ty + j*8)*Kd + k0 + tx] = __float2bfloat16(tile[tx][ty + j*8]);
}

// ---------------- MFMA GEMM: C[M,N] = A[M,K] @ B^T ; dtype-gated ----------------
// A row-major bf16 [M,K]; B row-major bf16 [N,K] (pre-transposed weight).
// Both staged via global_load_lds width 16 (m97 structure: 128x128, BK=32).
// VTRANS=1: C written transposed into VT[b][kh][d][s] (bf16), for the V proj.
template<typename TC, int VTRANS>
__global__ __launch_bounds__(256)
void gemm_bt(const int* __restrict__ flag, int mydt,
             const bf16* __restrict__ A, const bf16* __restrict__ Bm,
             TC* __restrict__ C, int M, int N, int K)
{
  if (*flag != mydt) return;
  __shared__ __align__(16) bf16 As[128*32];
  __shared__ __align__(16) bf16 Bs[128*32];
  const int tid  = threadIdx.x;
  const int w    = tid >> 6;
  const int lane = tid & 63;
  const int wr = w >> 1, wc = w & 1;
  const int tM = blockIdx.y*128, tN = blockIdx.x*128;
  const int srow = tid >> 2;          // 0..63
  const int scol = (tid & 3) * 8;     // 0,8,16,24
  const int fr = lane & 15;
  const int kq = (lane >> 4) * 8;

  f32x4 acc[4][4] = {};

  for (int k0 = 0; k0 < K; k0 += 32) {
    __syncthreads();
    #pragma unroll
    for (int q = 0; q < 2; q++) {
      const int row = q*64 + srow;
      const bf16* ga = A  + (size_t)(tM + row)*K + k0 + scol;
      const bf16* gb = Bm + (size_t)(tN + row)*K + k0 + scol;
      char* la = (char*)As + q*4096 + w*1024;   // wave-uniform base; HW adds lane*16
      char* lb = (char*)Bs + q*4096 + w*1024;
      __builtin_amdgcn_global_load_lds((const __attribute__((address_space(1))) void*)ga,
                                       (__attribute__((address_space(3))) void*)la, 16, 0, 0);
      __builtin_amdgcn_global_load_lds((const __attribute__((address_space(1))) void*)gb,
                                       (__attribute__((address_space(3))) void*)lb, 16, 0, 0);
    }
    __syncthreads();

    short8 af[4], bfr[4];
    #pragma unroll
    for (int m = 0; m < 4; m++) af[m]  = *(const short8*)&As[(wr*64 + m*16 + fr)*32 + kq];
    #pragma unroll
    for (int n = 0; n < 4; n++) bfr[n] = *(const short8*)&Bs[(wc*64 + n*16 + fr)*32 + kq];
    #pragma unroll
    for (int m = 0; m < 4; m++)
      #pragma unroll
      for (int n = 0; n < 4; n++)
        acc[m][n] = __builtin_amdgcn_mfma_f32_16x16x32_bf16(af[m], bfr[n], acc[m][n], 0, 0, 0);
  }

  // C/D layout: col = lane&15, row = (lane>>4)*4 + reg
  const int fq = lane >> 4;
  #pragma unroll
  for (int m = 0; m < 4; m++)
    #pragma unroll
    for (int n = 0; n < 4; n++)
      #pragma unroll
      for (int r = 0; r < 4; r++) {
        const int gm = tM + wr*64 + m*16 + fq*4 + r;
        const int gn = tN + wc*64 + n*16 + fr;
        if constexpr (VTRANS) {
          // VT[b][kh][d][s]: b=gm>>11, s=gm&2047, kh=gn>>7, d=gn&127
          size_t idx = ((size_t)((gm >> 11)*NKV + (gn >> 7)))*((size_t)HD*SS)
                     + (size_t)(gn & 127)*SS + (gm & 2047);
          stf((bf16*)C + idx, acc[m][n][r]);
        } else {
          stf(C + (size_t)gm*N + gn, acc[m][n][r]);
        }
      }
}

// ---------------- RoPE (in place, bf16 [MROWS, nh*HD]) ----------------
// inv_freq = 10000^(-f/64) = exp2(-f * log2(10000)/64); fast sincos.
__global__ void rope_kernel(bf16* __restrict__ X, int nh)
{
  int idx = blockIdx.x*blockDim.x + threadIdx.x;
  int total = MROWS * nh * 64;
  if (idx >= total) return;
  int f   = idx & 63;
  int h   = (idx >> 6) % nh;
  int row = (idx >> 6) / nh;
  int s   = row & (SS - 1);
  float ang = (float)s * exp2f((float)f * -0.20762050593046014f);
  float sv, cv;
  __sincosf(ang, &sv, &cv);
  size_t base = (size_t)row*nh*HD + (size_t)h*HD;
  float x1 = ldf(X + base + f), x2 = ldf(X + base + 64 + f);
  stf(X + base + f,      x1*cv - x2*sv);
  stf(X + base + 64 + f, x2*cv + x1*sv);
}

// ---------------- Flash-tile MFMA attention ----------------
// Block = (b, h, 64-row q-tile); 4 waves x 16 q-rows; KV tiles of 64.
// Q,K staged [64][128] swizzled (byte ^= (row&7)<<4); V^T staged [128][64]
// swizzled from pre-transposed VT; P via per-wave swizzled LDS round-trip.
__global__ __launch_bounds__(256, 2)
void attn_mfma(const bf16* __restrict__ Q, const bf16* __restrict__ K,
               const bf16* __restrict__ VT, bf16* __restrict__ Aout)
{
  const int i0 = blockIdx.x * 64;
  const int h  = blockIdx.y;
  const int b  = blockIdx.z;
  const int kh = h >> 2;
  const int tid = threadIdx.x;
  const int w = tid >> 6, lane = tid & 63;
  const int fr = lane & 15, fq = lane >> 4;

  __shared__ __align__(16) bf16 Qs[64*128];
  __shared__ __align__(16) bf16 Ks[64*128];
  __shared__ __align__(16) bf16 Vs[128*64];
  __shared__ __align__(16) bf16 Ps[4][16*64];

  // ---- stage Q tile (once), swizzled ----
  {
    const bf16* gq = Q + (size_t)(b*SS + i0)*HH + h*HD;
    #pragma unroll
    for (int it = 0; it < 4; it++) {
      int slot = tid + it*256;
      int r = slot >> 4, cg = slot & 15;
      short8 v = *(const short8*)(gq + (size_t)r*HH + cg*8);
      *(short8*)((char*)Qs + r*256 + ((cg*16) ^ ((r & 7) << 4))) = v;
    }
  }
  __syncthreads();

  // Q A-fragments (registers, reused across all KV tiles)
  short8 qf[4];
  {
    const int qrow = w*16 + fr;
    #pragma unroll
    for (int kk = 0; kk < 4; kk++)
      qf[kk] = *(const short8*)((char*)Qs + qrow*256 + ((kk*64 + fq*16) ^ ((qrow & 7) << 4)));
  }

  const float scale = 0.08838834764831845f;   // 1/sqrt(128)
  f32x4 o[8];
  #pragma unroll
  for (int nn = 0; nn < 8; nn++) o[nn] = (f32x4){0.f, 0.f, 0.f, 0.f};
  float m_run[4] = {-1e30f, -1e30f, -1e30f, -1e30f};
  float l_run[4] = {0.f, 0.f, 0.f, 0.f};

  const int j0_lo = (i0 >= WIN) ? (i0 - WIN) : 0;

  for (int j0 = j0_lo; j0 <= i0; j0 += 64) {
    __syncthreads();
    // ---- stage K tile [64][128] swizzled ----
    {
      const bf16* gk = K + (size_t)(b*SS + j0)*KVD + kh*HD;
      #pragma unroll
      for (int it = 0; it < 4; it++) {
        int slot = tid + it*256;
        int r = slot >> 4, cg = slot & 15;
        short8 v = *(const short8*)(gk + (size_t)r*KVD + cg*8);
        *(short8*)((char*)Ks + r*256 + ((cg*16) ^ ((r & 7) << 4))) = v;
      }
    }
    // ---- stage V^T tile [128][64] swizzled ----
    {
      const bf16* gv = VT + ((size_t)(b*NKV + kh)*HD)*SS + j0;
      #pragma unroll
      for (int it = 0; it < 4; it++) {
        int slot = tid + it*256;
        int d = slot >> 3, jg = slot & 7;
        short8 v = *(const short8*)(gv + (size_t)d*SS + jg*8);
        *(short8*)((char*)Vs + d*128 + ((jg*16) ^ ((d & 7) << 4))) = v;
      }
    }
    __syncthreads();

    // ---- QK^T: S[q=fq*4+r][j=jf*16+fr] ----
    f32x4 sv[4];
    #pragma unroll
    for (int jf = 0; jf < 4; jf++) sv[jf] = (f32x4){0.f, 0.f, 0.f, 0.f};
    #pragma unroll
    for (int kk = 0; kk < 4; kk++) {
      #pragma unroll
      for (int jf = 0; jf < 4; jf++) {
        const int krow = jf*16 + fr;
        short8 kf = *(const short8*)((char*)Ks + krow*256 + ((kk*64 + fq*16) ^ ((krow & 7) << 4)));
        sv[jf] = __builtin_amdgcn_mfma_f32_16x16x32_bf16(qf[kk], kf, sv[jf], 0, 0, 0);
      }
    }

    // ---- scale + mask ----
    const bool needmask = !((j0 >= i0 - 448) && (j0 <= i0 - 64));
    #pragma unroll
    for (int jf = 0; jf < 4; jf++)
      #pragma unroll
      for (int r = 0; r < 4; r++) {
        float x = sv[jf][r] * scale;
        if (needmask) {
          int iq = i0 + w*16 + fq*4 + r;
          int jv = j0 + jf*16 + fr;
          if (jv > iq || iq - jv > WIN) x = -1e30f;
        }
        sv[jf][r] = x;
      }

    // ---- online softmax (rows q = fq*4+r; in-reg + 16-lane xor reduce) ----
    float fac[4];
    #pragma unroll
    for (int r = 0; r < 4; r++) {
      float t = fmaxf(fmaxf(sv[0][r], sv[1][r]), fmaxf(sv[2][r], sv[3][r]));
      t = fmaxf(t, __shfl_xor(t, 1));
      t = fmaxf(t, __shfl_xor(t, 2));
      t = fmaxf(t, __shfl_xor(t, 4));
      t = fmaxf(t, __shfl_xor(t, 8));
      float mn = fmaxf(m_run[r], t);
      fac[r] = __expf(m_run[r] - mn);
      m_run[r] = mn;
    }
    #pragma unroll
    for (int r = 0; r < 4; r++) {
      float sum = 0.f;
      #pragma unroll
      for (int jf = 0; jf < 4; jf++) {
        float p = __expf(sv[jf][r] - m_run[r]);
        sv[jf][r] = p;
        sum += p;
      }
      sum += __shfl_xor(sum, 1);
      sum += __shfl_xor(sum, 2);
      sum += __shfl_xor(sum, 4);
      sum += __shfl_xor(sum, 8);
      l_run[r] = l_run[r]*fac[r] + sum;
    }

    // ---- P -> per-wave LDS (swizzled), reach A-operand layout ----
    char* pbase = (char*)(&Ps[w][0]);
    #pragma unroll
    for (int jf = 0; jf < 4; jf++)
      #pragma unroll
      for (int r = 0; r < 4; r++) {
        int q = fq*4 + r, j = jf*16 + fr;
        *(bf16*)(pbase + q*128 + ((j*2) ^ ((q & 7) << 4))) = __float2bfloat16(sv[jf][r]);
      }

    // ---- rescale O, then PV ----
    #pragma unroll
    for (int nn = 0; nn < 8; nn++)
      #pragma unroll
      for (int r = 0; r < 4; r++) o[nn][r] *= fac[r];

    #pragma unroll
    for (int kt = 0; kt < 2; kt++) {
      short8 ap = *(const short8*)(pbase + fr*128 + ((kt*64 + fq*16) ^ ((fr & 7) << 4)));
      #pragma unroll
      for (int nn = 0; nn < 8; nn++) {
        const int d = nn*16 + fr;
        short8 vf = *(const short8*)((char*)Vs + d*128 + ((kt*64 + fq*16) ^ ((d & 7) << 4)));
        o[nn] = __builtin_amdgcn_mfma_f32_16x16x32_bf16(ap, vf, o[nn], 0, 0, 0);
      }
    }
  }

  // ---- epilogue: O / l ----
  float inv[4];
  #pragma unroll
  for (int r = 0; r < 4; r++) inv[r] = 1.0f / l_run[r];
  bf16* ao = Aout + (size_t)(b*SS + i0 + w*16)*HH + h*HD;
  #pragma unroll
  for (int nn = 0; nn < 8; nn++)
    #pragma unroll
    for (int r = 0; r < 4; r++)
      stf(ao + (size_t)(fq*4 + r)*HH + nn*16 + fr, o[nn][r] * inv[r]);
}

extern "C" void kernel_launch(void* const* d_in, const int* in_sizes, int n_in,
                              void* d_out, int out_size, void* d_ws, size_t ws_size,
                              hipStream_t stream)
{
  // Workspace (80 MB + 256 B, prior-proven footprint):
  // flag @0 | Q @256 (32MB) | K (8MB) | VT (8MB) | S (32MB).
  // S time-shares: WTq -> WTk -> WTv -> attention output A. WTo reuses Q region.
  // fp32 mode: Xb (bf16 X, 32MB) lives in d_out (64MB fp32, dead until O-proj).
  char* ws = (char*)d_ws;
  const size_t MB = (size_t)1 << 20;
  int*  flag = (int*)ws;
  bf16* Q  = (bf16*)(ws + 256);
  bf16* K  = (bf16*)(ws + 256 + 32*MB);
  bf16* VT = (bf16*)(ws + 256 + 40*MB);
  bf16* S  = (bf16*)(ws + 256 + 48*MB);
  bf16* WTo = Q;
  bf16* Xb = (bf16*)d_out;              // fp32-mode scratch only (gated)

  detect_kernel<<<1, 256, 0, stream>>>(d_in[1], flag);
  cvt_x<<<MROWS*HH/8/256, 256, 0, stream>>>(flag, (const float*)d_in[0], Xb);

  auto tr = [&](const void* W, int Kd, int Nd, bf16* dst){
    dim3 g(Nd/32, Kd/32);
    transpose_cvt<bf16 ><<<g,256,0,stream>>>(flag, DT_BF16, (const bf16 *)W, dst, Kd, Nd);
    transpose_cvt<float><<<g,256,0,stream>>>(flag, DT_F32 , (const float*)W, dst, Kd, Nd);
  };
  // gemm over both dtype gates: bf16 mode reads A=d_in[0]; fp32 mode reads A=Xb.
  auto gemm2 = [&](bf16* Cm, int N){
    dim3 g(N/128, MROWS/128);
    gemm_bt<bf16,0><<<g,256,0,stream>>>(flag, DT_BF16, (const bf16*)d_in[0], S, Cm, MROWS, N, HH);
    gemm_bt<bf16,0><<<g,256,0,stream>>>(flag, DT_F32 , Xb,                   S, Cm, MROWS, N, HH);
  };

  // ---- projections ----
  tr(d_in[1], HH, HH, S);   gemm2(Q, HH);
  tr(d_in[2], HH, KVD, S);  gemm2(K, KVD);
  tr(d_in[3], HH, KVD, S);  // V projection writes V^T directly (VT[b][kh][d][s])
  {
    dim3 g(KVD/128, MROWS/128);
    gemm_bt<bf16,1><<<g,256,0,stream>>>(flag, DT_BF16, (const bf16*)d_in[0], S, VT, MROWS, KVD, HH);
    gemm_bt<bf16,1><<<g,256,0,stream>>>(flag, DT_F32 , Xb,                   S, VT, MROWS, KVD, HH);
  }

  // ---- dtype-independent middle ----
  rope_kernel<<<(MROWS*NH *64 + 255)/256, 256, 0, stream>>>(Q, NH);
  rope_kernel<<<(MROWS*NKV*64 + 255)/256, 256, 0, stream>>>(K, NKV);
  attn_mfma<<<dim3(SS/64, NH, BB), 256, 0, stream>>>(Q, K, VT, S);   // A -> S

  // ---- output projection (output dtype follows input dtype; overwrites Xb) ----
  tr(d_in[4], HH, HH, WTo);
  gemm_bt<bf16 ,0><<<dim3(HH/128, MROWS/128),256,0,stream>>>(flag, DT_BF16, S, WTo, (bf16 *)d_out, MROWS, HH, HH);
  gemm_bt<float,0><<<dim3(HH/128, MROWS/128),256,0,stream>>>(flag, DT_F32 , S, WTo, (float*)d_out, MROWS, HH, HH);
}

// Round 5
// 787.959 us; speedup vs baseline: 11.2907x; 1.2029x over previous
//
#include <hip/hip_runtime.h>
#include <hip/hip_bf16.h>
#include <math.h>

#define BB 2
#define SS 2048
#define HH 4096
#define NH 32
#define NKV 8
#define HD 128
#define KVD (NKV*HD)    // 1024
#define WIN 512         // mask: j <= i && i-j <= 512
#define MROWS (BB*SS)   // 4096

#define DT_BF16 1
#define DT_F32  2

typedef __hip_bfloat16 bf16;
typedef __attribute__((ext_vector_type(8))) short short8;
typedef __attribute__((ext_vector_type(4))) float f32x4;

__device__ __forceinline__ float ldf(const bf16* p){ return __bfloat162float(*p); }
__device__ __forceinline__ float ldf(const float* p){ return *p; }
__device__ __forceinline__ void stf(bf16* p, float v){ *p = __float2bfloat16(v); }
__device__ __forceinline__ void stf(float* p, float v){ *p = v; }

// ---------- dtype detector (prior-session-proven) ----------
__global__ void detect_kernel(const void* __restrict__ w, int* __restrict__ flag)
{
  __shared__ int big;
  if (threadIdx.x == 0) big = 0;
  __syncthreads();
  const unsigned short* u = (const unsigned short*)w;
  for (int i = threadIdx.x; i < 2048; i += 256) {
    int ex = (u[i] >> 7) & 0xFF;
    if (ex >= 160) big = 1;
  }
  __syncthreads();
  if (threadIdx.x == 0) *flag = big ? DT_F32 : DT_BF16;
}

// ---------- X fp32 -> bf16 (gated: fp32 mode only; Y = d_out scratch) ----------
__global__ __launch_bounds__(256)
void cvt_x(const int* __restrict__ flag, const float* __restrict__ X,
           bf16* __restrict__ Y)
{
  if (*flag != DT_F32) return;
  const size_t idx = (size_t)blockIdx.x*256 + threadIdx.x;   // 8 floats/thread
  const f32x4 a = *(const f32x4*)(X + idx*8);
  const f32x4 b = *(const f32x4*)(X + idx*8 + 4);
  union { short8 s; bf16 h[8]; } u;
  #pragma unroll
  for (int j = 0; j < 4; j++) {
    u.h[j]     = __float2bfloat16(a[j]);
    u.h[j + 4] = __float2bfloat16(b[j]);
  }
  *(short8*)(Y + idx*8) = u.s;
}

// ------------- W [Kd,Nd] -> WT [Nd,Kd] bf16, dtype-gated -------------
template<typename TS>
__global__ __launch_bounds__(256)
void transpose_cvt(const int* __restrict__ flag, int mydt,
                   const TS* __restrict__ W, bf16* __restrict__ WT, int Kd, int Nd)
{
  if (*flag != mydt) return;
  __shared__ float tile[32][33];
  const int n0 = blockIdx.x*32, k0 = blockIdx.y*32;
  const int tx = threadIdx.x & 31, ty = threadIdx.x >> 5;   // ty 0..7
  #pragma unroll
  for (int j = 0; j < 4; j++)
    tile[ty + j*8][tx] = ldf(W + (size_t)(k0 + ty + j*8)*Nd + n0 + tx);
  __syncthreads();
  #pragma unroll
  for (int j = 0; j < 4; j++)
    WT[(size_t)(n0 + ty + j*8)*Kd + k0 + tx] = __float2bfloat16(tile[tx][ty + j*8]);
}

// ======================= 256x256 8-phase MFMA GEMM =======================
// C[M,N] = A[M,K] @ B^T. A,B row-major bf16 with K contiguous. BK=64, 512 thr
// (8 waves, 2M x 4N), per-wave 128x64 out. LDS 128 KiB: 2 dbuf x (A 256x64 +
// B 256x64) as 128-row halves. Counted vmcnt (T4), chunk-XOR swizzle both-
// sides (T2, rule #21), setprio around MFMA clusters (T5), raw s_barrier.
#define MFMA16(a,b,c) __builtin_amdgcn_mfma_f32_16x16x32_bf16(a,b,c,0,0,0)

template<typename TC>
__global__ __launch_bounds__(512)
void gemm256(const int* __restrict__ flag, int mydt,
             const bf16* __restrict__ A, const bf16* __restrict__ Bm,
             TC* __restrict__ C, int M, int N, int K)
{
  if (*flag != mydt) return;
  __shared__ __align__(16) bf16 lds[65536];   // 128 KiB; chunks of 16B: A 0..4095, B 4096..8191
  const int tid = threadIdx.x;
  const int w = tid >> 6, lane = tid & 63;
  const int wm = w >> 2, wn = w & 3;
  const int fr = lane & 15, fq = lane >> 4;

  // XCD-aware bijective swizzle (nwg = 256, divisible by 8)
  const int gx = gridDim.x;
  int wg = blockIdx.y*gx + blockIdx.x;
  const int cpx = (gx*gridDim.y) >> 3;
  wg = (wg & 7)*cpx + (wg >> 3);
  const int tM = (wg / gx)*256, tN = (wg % gx)*256;

  const int NT = K >> 6;   // K-tiles of 64

  // stage one half-tile: slot s (0=A.h0,1=A.h1,2=B.h0,3=B.h1) of K-tile tt.
  // LDS dest linear (wave-uniform base); global source pre-swizzled c^= (r&7);
  // readers apply the same involution -> both-sides rule (#21).
  auto stage = [&](int tt, int s){
    const int dbuf = tt & 1;
    const int hf = s & 1;
    const bf16* src = (s < 2) ? A : Bm;
    const int brow = ((s < 2) ? tM : tN) + hf*128;
    const int cbase = ((s < 2) ? 0 : 4096) + (dbuf*2 + hf)*1024;
    #pragma unroll
    for (int g = 0; g < 2; g++) {
      const int Ch = g*512 + tid;          // chunk 0..1023 within half-tile
      const int r = Ch >> 3, c = Ch & 7;
      const int cs = c ^ (r & 7);
      const bf16* gp = src + (size_t)(brow + r)*K + tt*64 + cs*8;
      char* lp = (char*)lds + (size_t)(cbase + g*512 + w*64)*16;   // + lane*16 by HW
      __builtin_amdgcn_global_load_lds((const __attribute__((address_space(1))) void*)gp,
                                       (__attribute__((address_space(3))) void*)lp, 16, 0, 0);
    }
  };
  auto rdA = [&](int dbuf, int m, int kk) -> short8 {
    const int r = m*16 + fr;                       // row within half (half = wm)
    const int chunk = (dbuf*2 + wm)*1024 + r*8 + ((kk*4 + fq) ^ (r & 7));
    return *(const short8*)((char*)lds + (size_t)chunk*16);
  };
  auto rdB = [&](int dbuf, int n, int kk) -> short8 {
    const int rg = wn*64 + n*16 + fr;              // 0..255
    const int hf = rg >> 7, rr = rg & 127;
    const int chunk = 4096 + (dbuf*2 + hf)*1024 + rr*8 + ((kk*4 + fq) ^ (rr & 7));
    return *(const short8*)((char*)lds + (size_t)chunk*16);
  };

  f32x4 acc[8][4] = {};

  // ---- prologue: K-tile0 fully + K-tile1 A-halves; wait oldest 8 (tile0) ----
  #pragma unroll
  for (int s = 0; s < 4; s++) stage(0, s);
  stage(1, 0); stage(1, 1);
  asm volatile("s_waitcnt vmcnt(4)" ::: "memory");
  __builtin_amdgcn_s_barrier();

  short8 a0[4][2], a1[4][2], b0[2][2], b1[2][2];
  for (int kt = 0; kt < NT; kt++) {
    const int db = kt & 1;
    // -- phase 0: read A m0-3 + B n0-1; stage (kt+1).B.h0; MFMA quad (m0-3 x n0-1)
    #pragma unroll
    for (int m = 0; m < 4; m++){ a0[m][0]=rdA(db,m,0); a0[m][1]=rdA(db,m,1); }
    #pragma unroll
    for (int n = 0; n < 2; n++){ b0[n][0]=rdB(db,n,0); b0[n][1]=rdB(db,n,1); }
    if (kt+1 < NT) stage(kt+1, 2);
    asm volatile("s_waitcnt lgkmcnt(0)" ::: "memory");
    __builtin_amdgcn_sched_barrier(0);
    __builtin_amdgcn_s_setprio(1);
    #pragma unroll
    for (int m = 0; m < 4; m++)
      #pragma unroll
      for (int n = 0; n < 2; n++){
        acc[m][n] = MFMA16(a0[m][0], b0[n][0], acc[m][n]);
        acc[m][n] = MFMA16(a0[m][1], b0[n][1], acc[m][n]);
      }
    __builtin_amdgcn_s_setprio(0);
    __builtin_amdgcn_s_barrier();
    // -- phase 1: read A m4-7 + B n2-3; stage (kt+1).B.h1; MFMA quad (m4-7 x n2-3)
    #pragma unroll
    for (int m = 0; m < 4; m++){ a1[m][0]=rdA(db,m+4,0); a1[m][1]=rdA(db,m+4,1); }
    #pragma unroll
    for (int n = 0; n < 2; n++){ b1[n][0]=rdB(db,n+2,0); b1[n][1]=rdB(db,n+2,1); }
    if (kt+1 < NT) stage(kt+1, 3);
    asm volatile("s_waitcnt lgkmcnt(0)" ::: "memory");
    __builtin_amdgcn_sched_barrier(0);
    __builtin_amdgcn_s_setprio(1);
    #pragma unroll
    for (int m = 0; m < 4; m++)
      #pragma unroll
      for (int n = 0; n < 2; n++){
        acc[m+4][n+2] = MFMA16(a1[m][0], b1[n][0], acc[m+4][n+2]);
        acc[m+4][n+2] = MFMA16(a1[m][1], b1[n][1], acc[m+4][n+2]);
      }
    __builtin_amdgcn_s_setprio(0);
    __builtin_amdgcn_s_barrier();       // all dbuf(kt) LDS reads complete chip-wide
    // -- phase 2: stage (kt+2).A.h0 (same dbuf, now dead); MFMA quad (m0-3 x n2-3)
    if (kt+2 < NT) stage(kt+2, 0);
    __builtin_amdgcn_s_setprio(1);
    #pragma unroll
    for (int m = 0; m < 4; m++)
      #pragma unroll
      for (int n = 0; n < 2; n++){
        acc[m][n+2] = MFMA16(a0[m][0], b1[n][0], acc[m][n+2]);
        acc[m][n+2] = MFMA16(a0[m][1], b1[n][1], acc[m][n+2]);
      }
    __builtin_amdgcn_s_setprio(0);
    __builtin_amdgcn_s_barrier();
    // -- phase 3: stage (kt+2).A.h1; MFMA quad (m4-7 x n0-1)
    if (kt+2 < NT) stage(kt+2, 1);
    __builtin_amdgcn_s_setprio(1);
    #pragma unroll
    for (int m = 0; m < 4; m++)
      #pragma unroll
      for (int n = 0; n < 2; n++){
        acc[m+4][n] = MFMA16(a1[m][0], b0[n][0], acc[m+4][n]);
        acc[m+4][n] = MFMA16(a1[m][1], b0[n][1], acc[m+4][n]);
      }
    __builtin_amdgcn_s_setprio(0);
    // -- K-tile boundary: counted wait (never 0 in steady state) + barrier
    if (kt+2 < NT) { asm volatile("s_waitcnt vmcnt(4)" ::: "memory"); }
    else           { asm volatile("s_waitcnt vmcnt(0)" ::: "memory"); }
    __builtin_amdgcn_s_barrier();
  }

  // ---- epilogue: C/D layout col=lane&15, row=(lane>>4)*4+reg ----
  #pragma unroll
  for (int m = 0; m < 8; m++)
    #pragma unroll
    for (int n = 0; n < 4; n++)
      #pragma unroll
      for (int r = 0; r < 4; r++)
        stf(C + (size_t)(tM + wm*128 + m*16 + fq*4 + r)*N + (tN + wn*64 + n*16 + fr),
            acc[m][n][r]);
}

// ---------------- 128x128 MFMA GEMM (m97 structure) for K/V proj ----------------
// VTRANS=1: C written transposed into VT[b][kh][d][s] (bf16), for the V proj.
template<typename TC, int VTRANS>
__global__ __launch_bounds__(256)
void gemm_bt(const int* __restrict__ flag, int mydt,
             const bf16* __restrict__ A, const bf16* __restrict__ Bm,
             TC* __restrict__ C, int M, int N, int K)
{
  if (*flag != mydt) return;
  __shared__ __align__(16) bf16 As[128*32];
  __shared__ __align__(16) bf16 Bs[128*32];
  const int tid  = threadIdx.x;
  const int w    = tid >> 6;
  const int lane = tid & 63;
  const int wr = w >> 1, wc = w & 1;
  const int tM = blockIdx.y*128, tN = blockIdx.x*128;
  const int srow = tid >> 2;          // 0..63
  const int scol = (tid & 3) * 8;     // 0,8,16,24
  const int fr = lane & 15;
  const int kq = (lane >> 4) * 8;

  f32x4 acc[4][4] = {};

  for (int k0 = 0; k0 < K; k0 += 32) {
    __syncthreads();
    #pragma unroll
    for (int q = 0; q < 2; q++) {
      const int row = q*64 + srow;
      const bf16* ga = A  + (size_t)(tM + row)*K + k0 + scol;
      const bf16* gb = Bm + (size_t)(tN + row)*K + k0 + scol;
      char* la = (char*)As + q*4096 + w*1024;   // wave-uniform base; HW adds lane*16
      char* lb = (char*)Bs + q*4096 + w*1024;
      __builtin_amdgcn_global_load_lds((const __attribute__((address_space(1))) void*)ga,
                                       (__attribute__((address_space(3))) void*)la, 16, 0, 0);
      __builtin_amdgcn_global_load_lds((const __attribute__((address_space(1))) void*)gb,
                                       (__attribute__((address_space(3))) void*)lb, 16, 0, 0);
    }
    __syncthreads();

    short8 af[4], bfr[4];
    #pragma unroll
    for (int m = 0; m < 4; m++) af[m]  = *(const short8*)&As[(wr*64 + m*16 + fr)*32 + kq];
    #pragma unroll
    for (int n = 0; n < 4; n++) bfr[n] = *(const short8*)&Bs[(wc*64 + n*16 + fr)*32 + kq];
    #pragma unroll
    for (int m = 0; m < 4; m++)
      #pragma unroll
      for (int n = 0; n < 4; n++)
        acc[m][n] = MFMA16(af[m], bfr[n], acc[m][n]);
  }

  const int fq = lane >> 4;
  #pragma unroll
  for (int m = 0; m < 4; m++)
    #pragma unroll
    for (int n = 0; n < 4; n++)
      #pragma unroll
      for (int r = 0; r < 4; r++) {
        const int gm = tM + wr*64 + m*16 + fq*4 + r;
        const int gn = tN + wc*64 + n*16 + fr;
        if constexpr (VTRANS) {
          // VT[b][kh][d][s]: b=gm>>11, s=gm&2047, kh=gn>>7, d=gn&127
          size_t idx = ((size_t)((gm >> 11)*NKV + (gn >> 7)))*((size_t)HD*SS)
                     + (size_t)(gn & 127)*SS + (gm & 2047);
          stf((bf16*)C + idx, acc[m][n][r]);
        } else {
          stf(C + (size_t)gm*N + gn, acc[m][n][r]);
        }
      }
}

// ---------------- RoPE (in place, bf16 [MROWS, nh*HD]) ----------------
__global__ void rope_kernel(bf16* __restrict__ X, int nh)
{
  int idx = blockIdx.x*blockDim.x + threadIdx.x;
  int total = MROWS * nh * 64;
  if (idx >= total) return;
  int f   = idx & 63;
  int h   = (idx >> 6) % nh;
  int row = (idx >> 6) / nh;
  int s   = row & (SS - 1);
  float ang = (float)s * exp2f((float)f * -0.20762050593046014f);
  float sv, cv;
  __sincosf(ang, &sv, &cv);
  size_t base = (size_t)row*nh*HD + (size_t)h*HD;
  float x1 = ldf(X + base + f), x2 = ldf(X + base + 64 + f);
  stf(X + base + f,      x1*cv - x2*sv);
  stf(X + base + 64 + f, x2*cv + x1*sv);
}

// ---------------- Flash-tile MFMA attention ----------------
__global__ __launch_bounds__(256, 2)
void attn_mfma(const bf16* __restrict__ Q, const bf16* __restrict__ K,
               const bf16* __restrict__ VT, bf16* __restrict__ Aout)
{
  const int i0 = blockIdx.x * 64;
  const int h  = blockIdx.y;
  const int b  = blockIdx.z;
  const int kh = h >> 2;
  const int tid = threadIdx.x;
  const int w = tid >> 6, lane = tid & 63;
  const int fr = lane & 15, fq = lane >> 4;

  __shared__ __align__(16) bf16 Qs[64*128];
  __shared__ __align__(16) bf16 Ks[64*128];
  __shared__ __align__(16) bf16 Vs[128*64];
  __shared__ __align__(16) bf16 Ps[4][16*64];

  // ---- stage Q tile (once), swizzled ----
  {
    const bf16* gq = Q + (size_t)(b*SS + i0)*HH + h*HD;
    #pragma unroll
    for (int it = 0; it < 4; it++) {
      int slot = tid + it*256;
      int r = slot >> 4, cg = slot & 15;
      short8 v = *(const short8*)(gq + (size_t)r*HH + cg*8);
      *(short8*)((char*)Qs + r*256 + ((cg*16) ^ ((r & 7) << 4))) = v;
    }
  }
  __syncthreads();

  short8 qf[4];
  {
    const int qrow = w*16 + fr;
    #pragma unroll
    for (int kk = 0; kk < 4; kk++)
      qf[kk] = *(const short8*)((char*)Qs + qrow*256 + ((kk*64 + fq*16) ^ ((qrow & 7) << 4)));
  }

  const float scale = 0.08838834764831845f;   // 1/sqrt(128)
  f32x4 o[8];
  #pragma unroll
  for (int nn = 0; nn < 8; nn++) o[nn] = (f32x4){0.f, 0.f, 0.f, 0.f};
  float m_run[4] = {-1e30f, -1e30f, -1e30f, -1e30f};
  float l_run[4] = {0.f, 0.f, 0.f, 0.f};

  const int j0_lo = (i0 >= WIN) ? (i0 - WIN) : 0;

  for (int j0 = j0_lo; j0 <= i0; j0 += 64) {
    __syncthreads();
    {
      const bf16* gk = K + (size_t)(b*SS + j0)*KVD + kh*HD;
      #pragma unroll
      for (int it = 0; it < 4; it++) {
        int slot = tid + it*256;
        int r = slot >> 4, cg = slot & 15;
        short8 v = *(const short8*)(gk + (size_t)r*KVD + cg*8);
        *(short8*)((char*)Ks + r*256 + ((cg*16) ^ ((r & 7) << 4))) = v;
      }
    }
    {
      const bf16* gv = VT + ((size_t)(b*NKV + kh)*HD)*SS + j0;
      #pragma unroll
      for (int it = 0; it < 4; it++) {
        int slot = tid + it*256;
        int d = slot >> 3, jg = slot & 7;
        short8 v = *(const short8*)(gv + (size_t)d*SS + jg*8);
        *(short8*)((char*)Vs + d*128 + ((jg*16) ^ ((d & 7) << 4))) = v;
      }
    }
    __syncthreads();

    f32x4 sv[4];
    #pragma unroll
    for (int jf = 0; jf < 4; jf++) sv[jf] = (f32x4){0.f, 0.f, 0.f, 0.f};
    #pragma unroll
    for (int kk = 0; kk < 4; kk++) {
      #pragma unroll
      for (int jf = 0; jf < 4; jf++) {
        const int krow = jf*16 + fr;
        short8 kf = *(const short8*)((char*)Ks + krow*256 + ((kk*64 + fq*16) ^ ((krow & 7) << 4)));
        sv[jf] = MFMA16(qf[kk], kf, sv[jf]);
      }
    }

    const bool needmask = !((j0 >= i0 - 448) && (j0 <= i0 - 64));
    #pragma unroll
    for (int jf = 0; jf < 4; jf++)
      #pragma unroll
      for (int r = 0; r < 4; r++) {
        float x = sv[jf][r] * scale;
        if (needmask) {
          int iq = i0 + w*16 + fq*4 + r;
          int jv = j0 + jf*16 + fr;
          if (jv > iq || iq - jv > WIN) x = -1e30f;
        }
        sv[jf][r] = x;
      }

    float fac[4];
    #pragma unroll
    for (int r = 0; r < 4; r++) {
      float t = fmaxf(fmaxf(sv[0][r], sv[1][r]), fmaxf(sv[2][r], sv[3][r]));
      t = fmaxf(t, __shfl_xor(t, 1));
      t = fmaxf(t, __shfl_xor(t, 2));
      t = fmaxf(t, __shfl_xor(t, 4));
      t = fmaxf(t, __shfl_xor(t, 8));
      float mn = fmaxf(m_run[r], t);
      fac[r] = __expf(m_run[r] - mn);
      m_run[r] = mn;
    }
    #pragma unroll
    for (int r = 0; r < 4; r++) {
      float sum = 0.f;
      #pragma unroll
      for (int jf = 0; jf < 4; jf++) {
        float p = __expf(sv[jf][r] - m_run[r]);
        sv[jf][r] = p;
        sum += p;
      }
      sum += __shfl_xor(sum, 1);
      sum += __shfl_xor(sum, 2);
      sum += __shfl_xor(sum, 4);
      sum += __shfl_xor(sum, 8);
      l_run[r] = l_run[r]*fac[r] + sum;
    }

    char* pbase = (char*)(&Ps[w][0]);
    #pragma unroll
    for (int jf = 0; jf < 4; jf++)
      #pragma unroll
      for (int r = 0; r < 4; r++) {
        int q = fq*4 + r, j = jf*16 + fr;
        *(bf16*)(pbase + q*128 + ((j*2) ^ ((q & 7) << 4))) = __float2bfloat16(sv[jf][r]);
      }

    #pragma unroll
    for (int nn = 0; nn < 8; nn++)
      #pragma unroll
      for (int r = 0; r < 4; r++) o[nn][r] *= fac[r];

    #pragma unroll
    for (int kt = 0; kt < 2; kt++) {
      short8 ap = *(const short8*)(pbase + fr*128 + ((kt*64 + fq*16) ^ ((fr & 7) << 4)));
      #pragma unroll
      for (int nn = 0; nn < 8; nn++) {
        const int d = nn*16 + fr;
        short8 vf = *(const short8*)((char*)Vs + d*128 + ((kt*64 + fq*16) ^ ((d & 7) << 4)));
        o[nn] = MFMA16(ap, vf, o[nn]);
      }
    }
  }

  float inv[4];
  #pragma unroll
  for (int r = 0; r < 4; r++) inv[r] = 1.0f / l_run[r];
  bf16* ao = Aout + (size_t)(b*SS + i0 + w*16)*HH + h*HD;
  #pragma unroll
  for (int nn = 0; nn < 8; nn++)
    #pragma unroll
    for (int r = 0; r < 4; r++)
      stf(ao + (size_t)(fq*4 + r)*HH + nn*16 + fr, o[nn][r] * inv[r]);
}

extern "C" void kernel_launch(void* const* d_in, const int* in_sizes, int n_in,
                              void* d_out, int out_size, void* d_ws, size_t ws_size,
                              hipStream_t stream)
{
  // Workspace (80 MB + 256 B, prior-proven footprint):
  // flag @0 | Q @256 (32MB) | K (8MB) | VT (8MB) | S (32MB).
  // S time-shares: WTq -> WTk -> WTv -> attention output A. WTo reuses Q region.
  // fp32 mode: Xb (bf16 X, 32MB) lives in d_out (64MB fp32, dead until O-proj).
  char* ws = (char*)d_ws;
  const size_t MB = (size_t)1 << 20;
  int*  flag = (int*)ws;
  bf16* Q  = (bf16*)(ws + 256);
  bf16* K  = (bf16*)(ws + 256 + 32*MB);
  bf16* VT = (bf16*)(ws + 256 + 40*MB);
  bf16* S  = (bf16*)(ws + 256 + 48*MB);
  bf16* WTo = Q;
  bf16* Xb = (bf16*)d_out;              // fp32-mode scratch only (gated)

  detect_kernel<<<1, 256, 0, stream>>>(d_in[1], flag);
  cvt_x<<<MROWS*HH/8/256, 256, 0, stream>>>(flag, (const float*)d_in[0], Xb);

  auto tr = [&](const void* W, int Kd, int Nd, bf16* dst){
    dim3 g(Nd/32, Kd/32);
    transpose_cvt<bf16 ><<<g,256,0,stream>>>(flag, DT_BF16, (const bf16 *)W, dst, Kd, Nd);
    transpose_cvt<float><<<g,256,0,stream>>>(flag, DT_F32 , (const float*)W, dst, Kd, Nd);
  };

  // ---- projections ----
  tr(d_in[1], HH, HH, S);   // Q proj: 4096^3 -> 256^2 8-phase
  {
    dim3 g(HH/256, MROWS/256);
    gemm256<bf16><<<g,512,0,stream>>>(flag, DT_BF16, (const bf16*)d_in[0], S, Q, MROWS, HH, HH);
    gemm256<bf16><<<g,512,0,stream>>>(flag, DT_F32 , Xb,                   S, Q, MROWS, HH, HH);
  }
  tr(d_in[2], HH, KVD, S);  // K proj: 128^2 (N=1024 -> 256 blocks)
  {
    dim3 g(KVD/128, MROWS/128);
    gemm_bt<bf16,0><<<g,256,0,stream>>>(flag, DT_BF16, (const bf16*)d_in[0], S, K, MROWS, KVD, HH);
    gemm_bt<bf16,0><<<g,256,0,stream>>>(flag, DT_F32 , Xb,                   S, K, MROWS, KVD, HH);
  }
  tr(d_in[3], HH, KVD, S);  // V proj writes V^T directly (VT[b][kh][d][s])
  {
    dim3 g(KVD/128, MROWS/128);
    gemm_bt<bf16,1><<<g,256,0,stream>>>(flag, DT_BF16, (const bf16*)d_in[0], S, VT, MROWS, KVD, HH);
    gemm_bt<bf16,1><<<g,256,0,stream>>>(flag, DT_F32 , Xb,                   S, VT, MROWS, KVD, HH);
  }

  // ---- dtype-independent middle ----
  rope_kernel<<<(MROWS*NH *64 + 255)/256, 256, 0, stream>>>(Q, NH);
  rope_kernel<<<(MROWS*NKV*64 + 255)/256, 256, 0, stream>>>(K, NKV);
  attn_mfma<<<dim3(SS/64, NH, BB), 256, 0, stream>>>(Q, K, VT, S);   // A -> S

  // ---- output projection: 256^2 8-phase (output dtype follows input dtype) ----
  tr(d_in[4], HH, HH, WTo);
  {
    dim3 g(HH/256, MROWS/256);
    gemm256<bf16 ><<<g,512,0,stream>>>(flag, DT_BF16, S, WTo, (bf16 *)d_out, MROWS, HH, HH);
    gemm256<float><<<g,512,0,stream>>>(flag, DT_F32 , S, WTo, (float*)d_out, MROWS, HH, HH);
  }
}

// Round 6
// 734.514 us; speedup vs baseline: 12.1123x; 1.0728x over previous
//
#include <hip/hip_runtime.h>
#include <hip/hip_bf16.h>
#include <math.h>

#define BB 2
#define SS 2048
#define HH 4096
#define NH 32
#define NKV 8
#define HD 128
#define KVD (NKV*HD)    // 1024
#define WIN 512         // mask: j <= i && i-j <= 512
#define MROWS (BB*SS)   // 4096

#define DT_BF16 1
#define DT_F32  2

typedef __hip_bfloat16 bf16;
typedef __attribute__((ext_vector_type(8))) short short8;
typedef __attribute__((ext_vector_type(4))) float f32x4;

__device__ __forceinline__ float ldf(const bf16* p){ return __bfloat162float(*p); }
__device__ __forceinline__ float ldf(const float* p){ return *p; }
__device__ __forceinline__ void stf(bf16* p, float v){ *p = __float2bfloat16(v); }
__device__ __forceinline__ void stf(float* p, float v){ *p = v; }

// ---------- dtype detector (prior-session-proven) ----------
__global__ void detect_kernel(const void* __restrict__ w, int* __restrict__ flag)
{
  __shared__ int big;
  if (threadIdx.x == 0) big = 0;
  __syncthreads();
  const unsigned short* u = (const unsigned short*)w;
  for (int i = threadIdx.x; i < 2048; i += 256) {
    int ex = (u[i] >> 7) & 0xFF;
    if (ex >= 160) big = 1;
  }
  __syncthreads();
  if (threadIdx.x == 0) *flag = big ? DT_F32 : DT_BF16;
}

// ---------- X fp32 -> bf16 (gated: fp32 mode only; Y = d_out scratch) ----------
__global__ __launch_bounds__(256)
void cvt_x(const int* __restrict__ flag, const float* __restrict__ X,
           bf16* __restrict__ Y)
{
  if (*flag != DT_F32) return;
  const size_t idx = (size_t)blockIdx.x*256 + threadIdx.x;   // 8 floats/thread
  const f32x4 a = *(const f32x4*)(X + idx*8);
  const f32x4 b = *(const f32x4*)(X + idx*8 + 4);
  union { short8 s; bf16 h[8]; } u;
  #pragma unroll
  for (int j = 0; j < 4; j++) {
    u.h[j]     = __float2bfloat16(a[j]);
    u.h[j + 4] = __float2bfloat16(b[j]);
  }
  *(short8*)(Y + idx*8) = u.s;
}

// ------------- W [Kd,Nd] -> WT [Nd,Kd] bf16, dtype-gated -------------
// Z=2 grid: blockIdx.z selects (W0->D0) or (W1->D1) for fused Wk/Wv transpose.
template<typename TS>
__global__ __launch_bounds__(256)
void transpose_cvt(const int* __restrict__ flag, int mydt,
                   const TS* __restrict__ W0, const TS* __restrict__ W1,
                   bf16* __restrict__ D0, bf16* __restrict__ D1, int Kd, int Nd)
{
  if (*flag != mydt) return;
  const TS* W  = blockIdx.z ? W1 : W0;
  bf16*    WT  = blockIdx.z ? D1 : D0;
  __shared__ float tile[32][33];
  const int n0 = blockIdx.x*32, k0 = blockIdx.y*32;
  const int tx = threadIdx.x & 31, ty = threadIdx.x >> 5;   // ty 0..7
  #pragma unroll
  for (int j = 0; j < 4; j++)
    tile[ty + j*8][tx] = ldf(W + (size_t)(k0 + ty + j*8)*Nd + n0 + tx);
  __syncthreads();
  #pragma unroll
  for (int j = 0; j < 4; j++)
    WT[(size_t)(n0 + ty + j*8)*Kd + k0 + tx] = __float2bfloat16(tile[tx][ty + j*8]);
}

// ======================= 256x256 8-phase MFMA GEMM =======================
// C[M,N] = A[M,K] @ B^T. A,B row-major bf16, K contiguous. BK=64, 512 thr
// (8 waves, 2M x 4N), per-wave 128x64 out. LDS 128 KiB (2 dbuf). Template
// parity with m201: per phase {ds_reads || stage -> [lgkmcnt(8)] -> barrier
// -> lgkmcnt(0) -> setprio/MFMA -> barrier}; counted vmcnt at boundary only.
#define MFMA16(a,b,c) __builtin_amdgcn_mfma_f32_16x16x32_bf16(a,b,c,0,0,0)

template<typename TC>
__global__ __launch_bounds__(512)
void gemm256(const int* __restrict__ flag, int mydt,
             const bf16* __restrict__ A, const bf16* __restrict__ Bm,
             TC* __restrict__ C, int M, int N, int K)
{
  if (*flag != mydt) return;
  __shared__ __align__(16) bf16 lds[65536];   // 128 KiB; 16B chunks: A 0..4095, B 4096..8191
  const int tid = threadIdx.x;
  const int w = tid >> 6, lane = tid & 63;
  const int wm = w >> 2, wn = w & 3;
  const int fr = lane & 15, fq = lane >> 4;

  // XCD-aware bijective swizzle (nwg = 256, divisible by 8)
  const int gx = gridDim.x;
  int wg = blockIdx.y*gx + blockIdx.x;
  const int cpx = (gx*gridDim.y) >> 3;
  wg = (wg & 7)*cpx + (wg >> 3);
  const int tM = (wg / gx)*256, tN = (wg % gx)*256;

  const int NT = K >> 6;   // K-tiles of 64

  // stage one half-tile: slot s (0=A.h0,1=A.h1,2=B.h0,3=B.h1) of K-tile tt.
  // LDS dest linear (wave-uniform base); global source pre-swizzled c ^= r&7;
  // readers apply the same involution (both-sides rule #21).
  auto stage = [&](int tt, int s){
    const int dbuf = tt & 1;
    const int hf = s & 1;
    const bf16* src = (s < 2) ? A : Bm;
    const int brow = ((s < 2) ? tM : tN) + hf*128;
    const int cbase = ((s < 2) ? 0 : 4096) + (dbuf*2 + hf)*1024;
    #pragma unroll
    for (int g = 0; g < 2; g++) {
      const int Ch = g*512 + tid;          // chunk 0..1023 within half-tile
      const int r = Ch >> 3, c = Ch & 7;
      const int cs = c ^ (r & 7);
      const bf16* gp = src + (size_t)(brow + r)*K + tt*64 + cs*8;
      char* lp = (char*)lds + (size_t)(cbase + g*512 + w*64)*16;   // + lane*16 by HW
      __builtin_amdgcn_global_load_lds((const __attribute__((address_space(1))) void*)gp,
                                       (__attribute__((address_space(3))) void*)lp, 16, 0, 0);
    }
  };
  auto rdA = [&](int dbuf, int m, int kk) -> short8 {
    const int r = m*16 + fr;                       // row within half (half = wm)
    const int chunk = (dbuf*2 + wm)*1024 + r*8 + ((kk*4 + fq) ^ (r & 7));
    return *(const short8*)((char*)lds + (size_t)chunk*16);
  };
  auto rdB = [&](int dbuf, int n, int kk) -> short8 {
    const int rg = wn*64 + n*16 + fr;              // 0..255
    const int hf = rg >> 7, rr = rg & 127;
    const int chunk = 4096 + (dbuf*2 + hf)*1024 + rr*8 + ((kk*4 + fq) ^ (rr & 7));
    return *(const short8*)((char*)lds + (size_t)chunk*16);
  };

  f32x4 acc[8][4] = {};

  // ---- prologue: K-tile0 fully + K-tile1 A-halves; wait oldest 8 (tile0) ----
  #pragma unroll
  for (int s = 0; s < 4; s++) stage(0, s);
  stage(1, 0); stage(1, 1);
  asm volatile("s_waitcnt vmcnt(4)" ::: "memory");
  __builtin_amdgcn_s_barrier();

  short8 a0[4][2], a1[4][2], b0[2][2], b1[2][2];
  for (int kt = 0; kt < NT; kt++) {
    const int db = kt & 1;
    // -- phase 0: reads a0+b0 (12 ds_reads); stage (kt+1).B.h0; MFMA m0-3 x n0-1
    #pragma unroll
    for (int m = 0; m < 4; m++){ a0[m][0]=rdA(db,m,0); a0[m][1]=rdA(db,m,1); }
    #pragma unroll
    for (int n = 0; n < 2; n++){ b0[n][0]=rdB(db,n,0); b0[n][1]=rdB(db,n,1); }
    if (kt+1 < NT) stage(kt+1, 2);
    asm volatile("s_waitcnt lgkmcnt(8)" ::: "memory");
    __builtin_amdgcn_s_barrier();
    asm volatile("s_waitcnt lgkmcnt(0)" ::: "memory");
    __builtin_amdgcn_sched_barrier(0);
    __builtin_amdgcn_s_setprio(1);
    #pragma unroll
    for (int m = 0; m < 4; m++)
      #pragma unroll
      for (int n = 0; n < 2; n++){
        acc[m][n] = MFMA16(a0[m][0], b0[n][0], acc[m][n]);
        acc[m][n] = MFMA16(a0[m][1], b0[n][1], acc[m][n]);
      }
    __builtin_amdgcn_s_setprio(0);
    __builtin_amdgcn_s_barrier();
    // -- phase 1: reads a1+b1 (12 ds_reads); stage (kt+1).B.h1; MFMA m4-7 x n2-3
    #pragma unroll
    for (int m = 0; m < 4; m++){ a1[m][0]=rdA(db,m+4,0); a1[m][1]=rdA(db,m+4,1); }
    #pragma unroll
    for (int n = 0; n < 2; n++){ b1[n][0]=rdB(db,n+2,0); b1[n][1]=rdB(db,n+2,1); }
    if (kt+1 < NT) stage(kt+1, 3);
    asm volatile("s_waitcnt lgkmcnt(8)" ::: "memory");
    __builtin_amdgcn_s_barrier();
    asm volatile("s_waitcnt lgkmcnt(0)" ::: "memory");
    __builtin_amdgcn_sched_barrier(0);
    __builtin_amdgcn_s_setprio(1);
    #pragma unroll
    for (int m = 0; m < 4; m++)
      #pragma unroll
      for (int n = 0; n < 2; n++){
        acc[m+4][n+2] = MFMA16(a1[m][0], b1[n][0], acc[m+4][n+2]);
        acc[m+4][n+2] = MFMA16(a1[m][1], b1[n][1], acc[m+4][n+2]);
      }
    __builtin_amdgcn_s_setprio(0);
    __builtin_amdgcn_s_barrier();
    // -- phase 2: stage (kt+2).A.h0; MFMA m0-3 x n2-3 (operands in regs)
    if (kt+2 < NT) stage(kt+2, 0);
    __builtin_amdgcn_s_barrier();
    __builtin_amdgcn_s_setprio(1);
    #pragma unroll
    for (int m = 0; m < 4; m++)
      #pragma unroll
      for (int n = 0; n < 2; n++){
        acc[m][n+2] = MFMA16(a0[m][0], b1[n][0], acc[m][n+2]);
        acc[m][n+2] = MFMA16(a0[m][1], b1[n][1], acc[m][n+2]);
      }
    __builtin_amdgcn_s_setprio(0);
    __builtin_amdgcn_s_barrier();
    // -- phase 3: stage (kt+2).A.h1; MFMA m4-7 x n0-1
    if (kt+2 < NT) stage(kt+2, 1);
    __builtin_amdgcn_s_barrier();
    __builtin_amdgcn_s_setprio(1);
    #pragma unroll
    for (int m = 0; m < 4; m++)
      #pragma unroll
      for (int n = 0; n < 2; n++){
        acc[m+4][n] = MFMA16(a1[m][0], b0[n][0], acc[m+4][n]);
        acc[m+4][n] = MFMA16(a1[m][1], b0[n][1], acc[m+4][n]);
      }
    __builtin_amdgcn_s_setprio(0);
    // -- K-tile boundary: counted wait (never 0 in steady state) + barrier
    if (kt+2 < NT) { asm volatile("s_waitcnt vmcnt(4)" ::: "memory"); }
    else           { asm volatile("s_waitcnt vmcnt(0)" ::: "memory"); }
    __builtin_amdgcn_s_barrier();
  }

  // ---- epilogue: C/D layout col=lane&15, row=(lane>>4)*4+reg ----
  #pragma unroll
  for (int m = 0; m < 8; m++)
    #pragma unroll
    for (int n = 0; n < 4; n++)
      #pragma unroll
      for (int r = 0; r < 4; r++)
        stf(C + (size_t)(tM + wm*128 + m*16 + fq*4 + r)*N + (tN + wn*64 + n*16 + fr),
            acc[m][n][r]);
}

// ---------------- Fused K+V projection (m97 128x128 structure) ----------------
// blockIdx.z: 0 -> K = X@WTk^T (row-major out); 1 -> V = X@WTv^T written
// transposed into VT[b][kh][d][s]. 512 blocks total -> 2 blocks/CU overlap.
__global__ __launch_bounds__(256)
void gemm_kv(const int* __restrict__ flag, int mydt, const bf16* __restrict__ A,
             const bf16* __restrict__ WTk, const bf16* __restrict__ WTv,
             bf16* __restrict__ Kout, bf16* __restrict__ VTout, int M, int N, int K)
{
  if (*flag != mydt) return;
  const bool vpath = blockIdx.z != 0;
  const bf16* Bm = vpath ? WTv : WTk;
  __shared__ __align__(16) bf16 As[128*32];
  __shared__ __align__(16) bf16 Bs[128*32];
  const int tid  = threadIdx.x;
  const int w    = tid >> 6;
  const int lane = tid & 63;
  const int wr = w >> 1, wc = w & 1;
  const int tM = blockIdx.y*128, tN = blockIdx.x*128;
  const int srow = tid >> 2;          // 0..63
  const int scol = (tid & 3) * 8;     // 0,8,16,24
  const int fr = lane & 15;
  const int kq = (lane >> 4) * 8;

  f32x4 acc[4][4] = {};

  for (int k0 = 0; k0 < K; k0 += 32) {
    __syncthreads();
    #pragma unroll
    for (int q = 0; q < 2; q++) {
      const int row = q*64 + srow;
      const bf16* ga = A  + (size_t)(tM + row)*K + k0 + scol;
      const bf16* gb = Bm + (size_t)(tN + row)*K + k0 + scol;
      char* la = (char*)As + q*4096 + w*1024;   // wave-uniform base; HW adds lane*16
      char* lb = (char*)Bs + q*4096 + w*1024;
      __builtin_amdgcn_global_load_lds((const __attribute__((address_space(1))) void*)ga,
                                       (__attribute__((address_space(3))) void*)la, 16, 0, 0);
      __builtin_amdgcn_global_load_lds((const __attribute__((address_space(1))) void*)gb,
                                       (__attribute__((address_space(3))) void*)lb, 16, 0, 0);
    }
    __syncthreads();

    short8 af[4], bfr[4];
    #pragma unroll
    for (int m = 0; m < 4; m++) af[m]  = *(const short8*)&As[(wr*64 + m*16 + fr)*32 + kq];
    #pragma unroll
    for (int n = 0; n < 4; n++) bfr[n] = *(const short8*)&Bs[(wc*64 + n*16 + fr)*32 + kq];
    #pragma unroll
    for (int m = 0; m < 4; m++)
      #pragma unroll
      for (int n = 0; n < 4; n++)
        acc[m][n] = MFMA16(af[m], bfr[n], acc[m][n]);
  }

  const int fq = lane >> 4;
  #pragma unroll
  for (int m = 0; m < 4; m++)
    #pragma unroll
    for (int n = 0; n < 4; n++)
      #pragma unroll
      for (int r = 0; r < 4; r++) {
        const int gm = tM + wr*64 + m*16 + fq*4 + r;
        const int gn = tN + wc*64 + n*16 + fr;
        if (vpath) {
          // VT[b][kh][d][s]: b=gm>>11, s=gm&2047, kh=gn>>7, d=gn&127
          size_t idx = ((size_t)((gm >> 11)*NKV + (gn >> 7)))*((size_t)HD*SS)
                     + (size_t)(gn & 127)*SS + (gm & 2047);
          stf(VTout + idx, acc[m][n][r]);
        } else {
          stf(Kout + (size_t)gm*N + gn, acc[m][n][r]);
        }
      }
}

// ---------------- RoPE (in place, bf16 [MROWS, nh*HD]) ----------------
__global__ void rope_kernel(bf16* __restrict__ X, int nh)
{
  int idx = blockIdx.x*blockDim.x + threadIdx.x;
  int total = MROWS * nh * 64;
  if (idx >= total) return;
  int f   = idx & 63;
  int h   = (idx >> 6) % nh;
  int row = (idx >> 6) / nh;
  int s   = row & (SS - 1);
  float ang = (float)s * exp2f((float)f * -0.20762050593046014f);
  float sv, cv;
  __sincosf(ang, &sv, &cv);
  size_t base = (size_t)row*nh*HD + (size_t)h*HD;
  float x1 = ldf(X + base + f), x2 = ldf(X + base + 64 + f);
  stf(X + base + f,      x1*cv - x2*sv);
  stf(X + base + 64 + f, x2*cv + x1*sv);
}

// ---------------- Flash-tile MFMA attention ----------------
__global__ __launch_bounds__(256, 2)
void attn_mfma(const bf16* __restrict__ Q, const bf16* __restrict__ K,
               const bf16* __restrict__ VT, bf16* __restrict__ Aout)
{
  const int i0 = blockIdx.x * 64;
  const int h  = blockIdx.y;
  const int b  = blockIdx.z;
  const int kh = h >> 2;
  const int tid = threadIdx.x;
  const int w = tid >> 6, lane = tid & 63;
  const int fr = lane & 15, fq = lane >> 4;

  __shared__ __align__(16) bf16 Qs[64*128];
  __shared__ __align__(16) bf16 Ks[64*128];
  __shared__ __align__(16) bf16 Vs[128*64];
  __shared__ __align__(16) bf16 Ps[4][16*64];

  {
    const bf16* gq = Q + (size_t)(b*SS + i0)*HH + h*HD;
    #pragma unroll
    for (int it = 0; it < 4; it++) {
      int slot = tid + it*256;
      int r = slot >> 4, cg = slot & 15;
      short8 v = *(const short8*)(gq + (size_t)r*HH + cg*8);
      *(short8*)((char*)Qs + r*256 + ((cg*16) ^ ((r & 7) << 4))) = v;
    }
  }
  __syncthreads();

  short8 qf[4];
  {
    const int qrow = w*16 + fr;
    #pragma unroll
    for (int kk = 0; kk < 4; kk++)
      qf[kk] = *(const short8*)((char*)Qs + qrow*256 + ((kk*64 + fq*16) ^ ((qrow & 7) << 4)));
  }

  const float scale = 0.08838834764831845f;   // 1/sqrt(128)
  f32x4 o[8];
  #pragma unroll
  for (int nn = 0; nn < 8; nn++) o[nn] = (f32x4){0.f, 0.f, 0.f, 0.f};
  float m_run[4] = {-1e30f, -1e30f, -1e30f, -1e30f};
  float l_run[4] = {0.f, 0.f, 0.f, 0.f};

  const int j0_lo = (i0 >= WIN) ? (i0 - WIN) : 0;

  for (int j0 = j0_lo; j0 <= i0; j0 += 64) {
    __syncthreads();
    {
      const bf16* gk = K + (size_t)(b*SS + j0)*KVD + kh*HD;
      #pragma unroll
      for (int it = 0; it < 4; it++) {
        int slot = tid + it*256;
        int r = slot >> 4, cg = slot & 15;
        short8 v = *(const short8*)(gk + (size_t)r*KVD + cg*8);
        *(short8*)((char*)Ks + r*256 + ((cg*16) ^ ((r & 7) << 4))) = v;
      }
    }
    {
      const bf16* gv = VT + ((size_t)(b*NKV + kh)*HD)*SS + j0;
      #pragma unroll
      for (int it = 0; it < 4; it++) {
        int slot = tid + it*256;
        int d = slot >> 3, jg = slot & 7;
        short8 v = *(const short8*)(gv + (size_t)d*SS + jg*8);
        *(short8*)((char*)Vs + d*128 + ((jg*16) ^ ((d & 7) << 4))) = v;
      }
    }
    __syncthreads();

    f32x4 sv[4];
    #pragma unroll
    for (int jf = 0; jf < 4; jf++) sv[jf] = (f32x4){0.f, 0.f, 0.f, 0.f};
    #pragma unroll
    for (int kk = 0; kk < 4; kk++) {
      #pragma unroll
      for (int jf = 0; jf < 4; jf++) {
        const int krow = jf*16 + fr;
        short8 kf = *(const short8*)((char*)Ks + krow*256 + ((kk*64 + fq*16) ^ ((krow & 7) << 4)));
        sv[jf] = MFMA16(qf[kk], kf, sv[jf]);
      }
    }

    const bool needmask = !((j0 >= i0 - 448) && (j0 <= i0 - 64));
    #pragma unroll
    for (int jf = 0; jf < 4; jf++)
      #pragma unroll
      for (int r = 0; r < 4; r++) {
        float x = sv[jf][r] * scale;
        if (needmask) {
          int iq = i0 + w*16 + fq*4 + r;
          int jv = j0 + jf*16 + fr;
          if (jv > iq || iq - jv > WIN) x = -1e30f;
        }
        sv[jf][r] = x;
      }

    float fac[4];
    #pragma unroll
    for (int r = 0; r < 4; r++) {
      float t = fmaxf(fmaxf(sv[0][r], sv[1][r]), fmaxf(sv[2][r], sv[3][r]));
      t = fmaxf(t, __shfl_xor(t, 1));
      t = fmaxf(t, __shfl_xor(t, 2));
      t = fmaxf(t, __shfl_xor(t, 4));
      t = fmaxf(t, __shfl_xor(t, 8));
      float mn = fmaxf(m_run[r], t);
      fac[r] = __expf(m_run[r] - mn);
      m_run[r] = mn;
    }
    #pragma unroll
    for (int r = 0; r < 4; r++) {
      float sum = 0.f;
      #pragma unroll
      for (int jf = 0; jf < 4; jf++) {
        float p = __expf(sv[jf][r] - m_run[r]);
        sv[jf][r] = p;
        sum += p;
      }
      sum += __shfl_xor(sum, 1);
      sum += __shfl_xor(sum, 2);
      sum += __shfl_xor(sum, 4);
      sum += __shfl_xor(sum, 8);
      l_run[r] = l_run[r]*fac[r] + sum;
    }

    char* pbase = (char*)(&Ps[w][0]);
    #pragma unroll
    for (int jf = 0; jf < 4; jf++)
      #pragma unroll
      for (int r = 0; r < 4; r++) {
        int q = fq*4 + r, j = jf*16 + fr;
        *(bf16*)(pbase + q*128 + ((j*2) ^ ((q & 7) << 4))) = __float2bfloat16(sv[jf][r]);
      }

    #pragma unroll
    for (int nn = 0; nn < 8; nn++)
      #pragma unroll
      for (int r = 0; r < 4; r++) o[nn][r] *= fac[r];

    #pragma unroll
    for (int kt = 0; kt < 2; kt++) {
      short8 ap = *(const short8*)(pbase + fr*128 + ((kt*64 + fq*16) ^ ((fr & 7) << 4)));
      #pragma unroll
      for (int nn = 0; nn < 8; nn++) {
        const int d = nn*16 + fr;
        short8 vf = *(const short8*)((char*)Vs + d*128 + ((kt*64 + fq*16) ^ ((d & 7) << 4)));
        o[nn] = MFMA16(ap, vf, o[nn]);
      }
    }
  }

  float inv[4];
  #pragma unroll
  for (int r = 0; r < 4; r++) inv[r] = 1.0f / l_run[r];
  bf16* ao = Aout + (size_t)(b*SS + i0 + w*16)*HH + h*HD;
  #pragma unroll
  for (int nn = 0; nn < 8; nn++)
    #pragma unroll
    for (int r = 0; r < 4; r++)
      stf(ao + (size_t)(fq*4 + r)*HH + nn*16 + fr, o[nn][r] * inv[r]);
}

extern "C" void kernel_launch(void* const* d_in, const int* in_sizes, int n_in,
                              void* d_out, int out_size, void* d_ws, size_t ws_size,
                              hipStream_t stream)
{
  // Workspace (80 MB + 256 B, prior-proven footprint):
  // flag @0 | Q @256 (32MB) | K (8MB) | VT (8MB) | S (32MB).
  // S time-shares: WTq -> {WTk, WTv} -> attention output A. WTo reuses Q region.
  // fp32 mode: Xb (bf16 X, 32MB) lives in d_out (64MB fp32, dead until O-proj).
  char* ws = (char*)d_ws;
  const size_t MB = (size_t)1 << 20;
  int*  flag = (int*)ws;
  bf16* Q  = (bf16*)(ws + 256);
  bf16* K  = (bf16*)(ws + 256 + 32*MB);
  bf16* VT = (bf16*)(ws + 256 + 40*MB);
  bf16* S  = (bf16*)(ws + 256 + 48*MB);
  bf16* WTk = S;                        // 8 MB
  bf16* WTv = S + (size_t)KVD*HH;       // 8 MB (KVD*HH elems = 8 MB)
  bf16* WTo = Q;
  bf16* Xb = (bf16*)d_out;              // fp32-mode scratch only (gated)

  detect_kernel<<<1, 256, 0, stream>>>(d_in[1], flag);
  cvt_x<<<MROWS*HH/8/256, 256, 0, stream>>>(flag, (const float*)d_in[0], Xb);

  auto tr1 = [&](const void* W, int Kd, int Nd, bf16* dst){
    dim3 g(Nd/32, Kd/32, 1);
    transpose_cvt<bf16 ><<<g,256,0,stream>>>(flag, DT_BF16, (const bf16 *)W, (const bf16 *)W, dst, dst, Kd, Nd);
    transpose_cvt<float><<<g,256,0,stream>>>(flag, DT_F32 , (const float*)W, (const float*)W, dst, dst, Kd, Nd);
  };

  // ---- Q projection: 4096^3 -> 256^2 8-phase ----
  tr1(d_in[1], HH, HH, S);
  {
    dim3 g(HH/256, MROWS/256);
    gemm256<bf16><<<g,512,0,stream>>>(flag, DT_BF16, (const bf16*)d_in[0], S, Q, MROWS, HH, HH);
    gemm256<bf16><<<g,512,0,stream>>>(flag, DT_F32 , Xb,                   S, Q, MROWS, HH, HH);
  }
  // ---- K+V projections fused: transpose both, then one 512-block dispatch ----
  {
    dim3 gt(KVD/32, HH/32, 2);
    transpose_cvt<bf16 ><<<gt,256,0,stream>>>(flag, DT_BF16, (const bf16 *)d_in[2], (const bf16 *)d_in[3], WTk, WTv, HH, KVD);
    transpose_cvt<float><<<gt,256,0,stream>>>(flag, DT_F32 , (const float*)d_in[2], (const float*)d_in[3], WTk, WTv, HH, KVD);
    dim3 g(KVD/128, MROWS/128, 2);
    gemm_kv<<<g,256,0,stream>>>(flag, DT_BF16, (const bf16*)d_in[0], WTk, WTv, K, VT, MROWS, KVD, HH);
    gemm_kv<<<g,256,0,stream>>>(flag, DT_F32 , Xb,                   WTk, WTv, K, VT, MROWS, KVD, HH);
  }

  // ---- dtype-independent middle ----
  rope_kernel<<<(MROWS*NH *64 + 255)/256, 256, 0, stream>>>(Q, NH);
  rope_kernel<<<(MROWS*NKV*64 + 255)/256, 256, 0, stream>>>(K, NKV);
  attn_mfma<<<dim3(SS/64, NH, BB), 256, 0, stream>>>(Q, K, VT, S);   // A -> S

  // ---- output projection: 256^2 8-phase (output dtype follows input dtype) ----
  tr1(d_in[4], HH, HH, WTo);
  {
    dim3 g(HH/256, MROWS/256);
    gemm256<bf16 ><<<g,512,0,stream>>>(flag, DT_BF16, S, WTo, (bf16 *)d_out, MROWS, HH, HH);
    gemm256<float><<<g,512,0,stream>>>(flag, DT_F32 , S, WTo, (float*)d_out, MROWS, HH, HH);
  }
}